// Round 3
// baseline (1054.762 us; speedup 1.0000x reference)
//
#include <hip/hip_runtime.h>

typedef unsigned short u16;
typedef unsigned int u32;
typedef unsigned long long u64;
typedef __attribute__((ext_vector_type(8))) short short8;
typedef __attribute__((ext_vector_type(4))) float floatx4;

__device__ __forceinline__ float b2f(u16 u) {
    u32 x = ((u32)u) << 16; float f; __builtin_memcpy(&f, &x, 4); return f;
}
__device__ __forceinline__ u16 f2b(float f) {
    u32 x; __builtin_memcpy(&x, &f, 4);
    u32 r = (x + 0x7fffu + ((x >> 16) & 1u)) >> 16;
    return (u16)r;
}
__device__ __forceinline__ float ldf(const void* p, long i, int isf) {
    return isf ? ((const float*)p)[i] : b2f(((const u16*)p)[i]);
}
__device__ __forceinline__ void stf(void* p, long i, float v, int isf) {
    if (isf) ((float*)p)[i] = v; else ((u16*)p)[i] = f2b(v);
}
__device__ __forceinline__ int ldidx(const int* w, long i, int is64) {
    return is64 ? w[2 * i] : w[i];
}
// async global->LDS, 16B per lane. LDS dst = wave-uniform base + lane*16.
__device__ __forceinline__ void gload16(const u16* g, u16* l) {
    __builtin_amdgcn_global_load_lds((const __attribute__((address_space(1))) void*)g,
                                     (__attribute__((address_space(3))) void*)l, 16, 0, 0);
}

// ---------------- dtype detection (1 wave) ----------------
__global__ void detect_kernel(const u32* __restrict__ xw, const u32* __restrict__ iw,
                              int* __restrict__ flags) {
    int lane = threadIdx.x;
    u32 w = xw[lane];
    u32 b1 = (w >> 8) & 0x7f;
    int isbf = (b1 >= 0x38 && b1 <= 0x41) ? 1 : 0;
    int cbf = __popcll(__ballot(isbf));
    u32 hi = iw[2 * lane + 1];
    int cz = __popcll(__ballot(hi == 0u));
    if (lane == 0) {
        flags[0] = (cbf < 32) ? 1 : 0;        // 1 = fp32
        flags[1] = (cz >= 56) ? 1 : 0;        // 1 = int64
    }
}

// ---------------- graph utility kernels ----------------

__global__ void count_kernel(const int* __restrict__ eiw, int E, int* __restrict__ cnt,
                             const int* __restrict__ flags) {
    int e = blockIdx.x * 256 + threadIdx.x;
    if (e < E) atomicAdd(&cnt[ldidx(eiw, (long)E + e, flags[1])], 1);
}

// fused: per-dst histogram + per-(segment, 128-dst-bucket) histogram.
// segment = blockIdx.x & 7 (empirically pinned to one XCD by round-robin dispatch).
__global__ void count2_kernel(const int* __restrict__ eiw, int E, int segLen,
                              int* __restrict__ cnt, int* __restrict__ sbCnt, int NB,
                              const int* __restrict__ flags) {
    int s = blockIdx.x & 7, c = blockIdx.x >> 3;
    int e = s * segLen + c * 256 + threadIdx.x;
    int eEnd = (s + 1) * segLen; if (eEnd > E) eEnd = E;
    if (e < eEnd) {
        int d = ldidx(eiw, (long)E + e, flags[1]);
        atomicAdd(&cnt[d], 1);
        atomicAdd(&sbCnt[s * NB + (d >> 7)], 1);
    }
}

// sbCur[s][b] = off1[b<<7] + sum_{s'<s} sbCnt[s'][b]
__global__ void subscan_kernel(const int* __restrict__ off1, const int* __restrict__ sbCnt,
                               int* __restrict__ sbCur, int NB, int N1) {
    int b = blockIdx.x * 256 + threadIdx.x;
    if (b >= NB) return;
    int d0 = b << 7; if (d0 > N1) d0 = N1;
    int base = off1[d0];
    for (int s = 0; s < 8; s++) { sbCur[s * NB + b] = base; base += sbCnt[s * NB + b]; }
}

// scatter packed (dlow<<17 | src) into bucket-major pair buffer. Each (seg,bucket)
// sub-region is written only from one XCD -> L2 write-coalescing, ~no amplification.
__global__ void presort_kernel(const int* __restrict__ eiw, int E, int segLen,
                               int* __restrict__ sbCur, int NB, u32* __restrict__ pair,
                               const int* __restrict__ flags) {
    int s = blockIdx.x & 7, c = blockIdx.x >> 3;
    int e = s * segLen + c * 256 + threadIdx.x;
    int eEnd = (s + 1) * segLen; if (eEnd > E) eEnd = E;
    if (e < eEnd) {
        int is64 = flags[1];
        int src = ldidx(eiw, e, is64);
        int d = ldidx(eiw, (long)E + e, is64);
        int p = atomicAdd(&sbCur[s * NB + (d >> 7)], 1);
        pair[p] = ((u32)(d & 127) << 17) | (u32)src;
    }
}

// final fill: one workgroup per bucket. LDS cursors (no global atomics); reads the
// bucket's contiguous pair range, writes the same contiguous elist range.
__global__ void bucketfill_kernel(const u32* __restrict__ pair, const int* __restrict__ off1,
                                  int NB, int N1, int E, int* __restrict__ elist) {
    __shared__ int soff[128];
    __shared__ int cur[128];
    int b = blockIdx.x, t = threadIdx.x;
    int d0 = b << 7;
    int nd = N1 - d0; if (nd > 128) nd = 128;
    if (t < nd) { soff[t] = off1[d0 + t]; cur[t] = 0; }
    __syncthreads();
    int hiD = d0 + 128; if (hiD > N1) hiD = N1;
    int lo = off1[d0], hi = off1[hiD];
    for (int i = lo + t; i < hi; i += 256) {
        u32 v = pair[i];
        int dlow = v >> 17, src = (int)(v & 0x1FFFFu);
        int p = atomicAdd(&cur[dlow], 1);
        elist[soff[dlow] + p] = src;
    }
}

__global__ void scan_block_kernel(const int* __restrict__ in, int* __restrict__ out,
                                  int* __restrict__ bsum, int n) {
    __shared__ int sm[1024];
    int t = threadIdx.x;
    int i = blockIdx.x * 1024 + t;
    int v = (i < n) ? in[i] : 0;
    sm[t] = v;
    __syncthreads();
    for (int o = 1; o < 1024; o <<= 1) {
        int x = (t >= o) ? sm[t - o] : 0;
        __syncthreads();
        sm[t] += x;
        __syncthreads();
    }
    if (i < n) out[i] = sm[t] - v;
    if (t == 1023) bsum[blockIdx.x] = sm[1023];
}

__global__ void scan_small_kernel(int* __restrict__ bsum, int nb) {
    __shared__ int sm[128];
    int t = threadIdx.x;
    int v = (t < nb) ? bsum[t] : 0;
    sm[t] = v;
    __syncthreads();
    for (int o = 1; o < 128; o <<= 1) {
        int x = (t >= o) ? sm[t - o] : 0;
        __syncthreads();
        sm[t] += x;
        __syncthreads();
    }
    if (t < nb) bsum[t] = sm[t] - v;
}

__global__ void scan_add_kernel(int* __restrict__ off, const int* __restrict__ bsum,
                                int n, int total) {
    int i = blockIdx.x * 1024 + threadIdx.x;
    if (i < n) off[i] += bsum[blockIdx.x];
    if (i == 0) off[n] = total;
}

// G2 fill: pack (src | type<<10) per edge, grouped by dst. src<1024, type<2^22.
__global__ void fill2_kernel(const int* __restrict__ ei, const int* __restrict__ et, int E,
                             const int* __restrict__ off, int* __restrict__ cur,
                             u32* __restrict__ elist, const int* __restrict__ flags) {
    int e = blockIdx.x * 256 + threadIdx.x;
    if (e < E) {
        int is64 = flags[1];
        int s = ldidx(ei, e, is64);
        int d = ldidx(ei, (long)E + e, is64);
        int t = ldidx(et, e, is64);
        int p = atomicAdd(&cur[d], 1);
        elist[off[d] + p] = (u32)s | ((u32)t << 10);
    }
}

// fp32->bf16x4 (or bf16 copy) vectorized convert
__global__ void cvt4_kernel(const void* __restrict__ in, u64* __restrict__ out, long n4,
                            const int* __restrict__ flags) {
    long i = (long)blockIdx.x * 256 + threadIdx.x;
    if (i >= n4) return;
    if (flags[0]) {
        float4 v = ((const float4*)in)[i];
        out[i] = (u64)f2b(v.x) | ((u64)f2b(v.y) << 16) | ((u64)f2b(v.z) << 32) |
                 ((u64)f2b(v.w) << 48);
    } else {
        out[i] = ((const u64*)in)[i];
    }
}

// mean-aggregate neighbor rows (128 feats per row, one wave per node), x in bf16 (xb)
// unless useXB==0 (then raw input via flags path).
__global__ void agg_kernel(const void* __restrict__ xraw, const u32* __restrict__ xb,
                           const int* __restrict__ off, const int* __restrict__ elist,
                           u32* __restrict__ aggbf, int N, const int* __restrict__ flags,
                           int useXB) {
    int node = blockIdx.x * 4 + (threadIdx.x >> 6);
    if (node >= N) return;
    int lane = threadIdx.x & 63;
    int b = off[node], e = off[node + 1];
    float a0 = 0.f, a1 = 0.f, c0 = 0.f, c1 = 0.f;
    if (useXB) {
        int i = b;
        for (; i + 4 <= e; i += 4) {
            int s0 = elist[i], s1 = elist[i + 1], s2 = elist[i + 2], s3 = elist[i + 3];
            u32 v0 = xb[(long)s0 * 64 + lane];
            u32 v1 = xb[(long)s1 * 64 + lane];
            u32 v2 = xb[(long)s2 * 64 + lane];
            u32 v3 = xb[(long)s3 * 64 + lane];
            a0 += b2f((u16)(v0 & 0xffffu)) + b2f((u16)(v2 & 0xffffu));
            a1 += b2f((u16)(v0 >> 16)) + b2f((u16)(v2 >> 16));
            c0 += b2f((u16)(v1 & 0xffffu)) + b2f((u16)(v3 & 0xffffu));
            c1 += b2f((u16)(v1 >> 16)) + b2f((u16)(v3 >> 16));
        }
        for (; i < e; i++) {
            u32 v = xb[(long)elist[i] * 64 + lane];
            a0 += b2f((u16)(v & 0xffffu));
            a1 += b2f((u16)(v >> 16));
        }
        a0 += c0; a1 += c1;
    } else if (flags[0]) {
        const float* xf = (const float*)xraw;
        for (int i = b; i < e; i++) {
            long s = elist[i];
            a0 += xf[s * 128 + 2 * lane];
            a1 += xf[s * 128 + 2 * lane + 1];
        }
    } else {
        const u32* xu = (const u32*)xraw;
        for (int i = b; i < e; i++) {
            u32 v = xu[(long)elist[i] * 64 + lane];
            a0 += b2f((u16)(v & 0xffffu));
            a1 += b2f((u16)(v >> 16));
        }
    }
    int dg = e - b; if (dg < 1) dg = 1;
    float inv = 1.0f / (float)dg;
    aggbf[(long)node * 64 + lane] = (u32)f2b(a0 * inv) | ((u32)f2b(a1 * inv) << 16);
}

// flag-aware transpose: in (bf16 or fp32) [R,C] at element offset inOff -> out bf16 [C,R]
__global__ void transpose_kernel(const void* __restrict__ in, long inOff,
                                 u16* __restrict__ out, int R, int C,
                                 const int* __restrict__ flags) {
    __shared__ u16 tile[32][33];
    int isf = flags[0];
    int tx = threadIdx.x, ty = threadIdx.y;
    int x = blockIdx.x * 32 + tx;
#pragma unroll
    for (int i = 0; i < 4; i++) {
        int y = blockIdx.y * 32 + ty + i * 8;
        long idx = inOff + (long)y * C + x;
        tile[ty + i * 8][tx] = isf ? f2b(((const float*)in)[idx]) : ((const u16*)in)[idx];
    }
    __syncthreads();
    int x2 = blockIdx.y * 32 + tx;
#pragma unroll
    for (int i = 0; i < 4; i++) {
        int y2 = blockIdx.x * 32 + ty + i * 8;
        out[(long)y2 * R + x2] = tile[tx][ty + i * 8];
    }
}

// dst-sorted dense-A build: one workgroup per dst row d. Accumulate CH basis rows
// A[b][d][:] in LDS (fp32, ds_add_f32 atomics -- no global atomics), then write
// bf16 directly (fuses the old convert_kernel; no Af memset needed).
__global__ __launch_bounds__(256)
void scatterA_lds_kernel(const u32* __restrict__ elist, const int* __restrict__ off,
                         const void* __restrict__ att, u16* __restrict__ Abf,
                         int b0, int CH, const int* __restrict__ flags) {
    __shared__ float sA[15 * 1024];
    const int d = blockIdx.x, t = threadIdx.x;
    const int b = off[d], e = off[d + 1];
    int cnt = e - b; if (cnt < 1) cnt = 1;
    const float inv = 1.0f / (float)cnt;
    const int tot = CH << 10;
    for (int i = t; i < tot; i += 256) sA[i] = 0.f;
    __syncthreads();
    const int isf = flags[0];
    for (int i = b + t; i < e; i += 256) {
        u32 v = elist[i];
        int s = v & 1023;
        long tb = (long)(v >> 10) * 30 + b0;
        for (int bb = 0; bb < CH; bb++)
            atomicAdd(&sA[(bb << 10) + s], ldf(att, tb + bb, isf) * inv);
    }
    __syncthreads();
    const long obase = (long)d * 256 + t;
    for (int bb = 0; bb < CH; bb++) {
        int base = (bb << 10) + (t << 2);
        u64 p = (u64)f2b(sA[base]) | ((u64)f2b(sA[base + 1]) << 16) |
                ((u64)f2b(sA[base + 2]) << 32) | ((u64)f2b(sA[base + 3]) << 48);
        ((u64*)Abf)[(long)bb * 262144 + obase] = p;
    }
}

// ---------------- MFMA GEMM: C = A @ B, B pre-transposed (BT[n][k]), bf16 inputs ----------------
// m97-style global_load_lds staging (16B/lane) into UNPADDED LDS [128][32] with XOR swizzle:
// chunk q (8 u16) of row r lives at slot (q ^ ((r>>1)&3)) -> frag ds_read_b128 is 2-way (free),
// staging is lane-linear as the DMA requires.
// Grid is remapped XCD-aware (bijective, m204): contiguous nbid ranges land on one XCD,
// decoded z-major/x-fastest so one XCD processes whole batches (A_z + XT fit its 4MB L2).
// MODE 0: fused bias+relu+log_softmax -> flag-aware out (part1)
// MODE 1: Cb[crow*ldc + bz*colOffDim + ccol] = bf16(acc)   (S_b packed wide)
// MODE 2: Cf = acc + bias[col]                             (root GEMM fp32)
// MODE 3: Cf[bz] += acc                                    (split-K accumulate)
// MODE 4: Cf[bz] = acc                                     (split-K first-chunk store)
template <int MODE>
__global__ __launch_bounds__(256)
void gemm_bt(const u16* __restrict__ A, long aBatch,
             const u16* __restrict__ BT,
             float* __restrict__ Cf, void* __restrict__ Cb,
             const void* __restrict__ bias, const int* __restrict__ flags,
             int M, int lda, int ldb, int ldc,
             int colOffDim, long cBatch, int kSplitStride, int kLen) {
    __shared__ u16 As[4096];
    __shared__ u16 Bs[4096];
    __shared__ float sred[2][2][128];
    const int t = threadIdx.x;
    // ---- bijective XCD-aware remap (round-robin bid%8 -> contiguous range) ----
    const int gx = gridDim.x, gy = gridDim.y;
    const int nwg = gx * gy * gridDim.z;
    const int bid = blockIdx.x + gx * (blockIdx.y + gy * blockIdx.z);
    const int q = nwg >> 3, r = nwg & 7;
    const int xcd = bid & 7, idx = bid >> 3;
    const int nbid = (xcd < r ? xcd * (q + 1) : r * (q + 1) + (xcd - r) * q) + idx;
    const int bx = nbid % gx;
    const int by = (nbid / gx) % gy;
    const int bz = nbid / (gx * gy);

    const int isf = flags[0];
    A += (long)bz * aBatch;
    const int kBase = bz * kSplitStride;
    const int row0 = bx * 128;
    const int n0 = by * 128;
    const int lane = t & 63, wave = t >> 6;
    const int wrow = (wave >> 1) * 64, wcol = (wave & 1) * 64;
    const int quad = lane >> 4, l16 = lane & 15;

    // staging: issue h covers LDS rows h*64 + wave*16 + (lane>>2), slot lane&3
    long aoff[2], boff[2];
    u16 *ldsA[2], *ldsB[2];
#pragma unroll
    for (int h = 0; h < 2; h++) {
        int r2 = h * 64 + wave * 16 + (lane >> 2);
        int clog = (lane & 3) ^ ((r2 >> 1) & 3);
        int ga = row0 + r2; if (ga >= M) ga = M - 1;
        aoff[h] = (long)ga * lda + clog * 8;
        boff[h] = (long)(n0 + r2) * ldb + clog * 8;
        ldsA[h] = &As[(h * 64 + wave * 16) * 32];
        ldsB[h] = &Bs[(h * 64 + wave * 16) * 32];
    }
    // fragment read offsets (u16 index), constant across K
    int aidx[4], bidx[4];
#pragma unroll
    for (int i = 0; i < 4; i++) {
        int ra = wrow + i * 16 + l16;
        aidx[i] = ra * 32 + ((quad ^ ((ra >> 1) & 3)) * 8);
        int rb = wcol + i * 16 + l16;
        bidx[i] = rb * 32 + ((quad ^ ((rb >> 1) & 3)) * 8);
    }

    floatx4 acc[4][4];
#pragma unroll
    for (int i = 0; i < 4; i++)
#pragma unroll
        for (int j = 0; j < 4; j++)
            acc[i][j] = (floatx4){0.f, 0.f, 0.f, 0.f};

    for (int kt = kBase; kt < kBase + kLen; kt += 32) {
        __syncthreads();
#pragma unroll
        for (int h = 0; h < 2; h++) {
            gload16(A + aoff[h] + kt, ldsA[h]);
            gload16(BT + boff[h] + kt, ldsB[h]);
        }
        __syncthreads();
        short8 af[4], bfr[4];
#pragma unroll
        for (int i = 0; i < 4; i++) {
            af[i]  = *(const short8*)&As[aidx[i]];
            bfr[i] = *(const short8*)&Bs[bidx[i]];
        }
#pragma unroll
        for (int i = 0; i < 4; i++)
#pragma unroll
            for (int j = 0; j < 4; j++)
                acc[i][j] = __builtin_amdgcn_mfma_f32_16x16x32_bf16(af[i], bfr[j], acc[i][j], 0, 0, 0);
    }

    if (MODE == 0) {
        const int colhalf = wave & 1;
        float bv[4];
#pragma unroll
        for (int j = 0; j < 4; j++)
            bv[j] = ldf(bias, wcol + j * 16 + l16, isf);
        float Mp[4][4];
#pragma unroll
        for (int i = 0; i < 4; i++)
#pragma unroll
            for (int rr = 0; rr < 4; rr++) {
                float m = 0.f;   // relu => 0 is a safe identity
#pragma unroll
                for (int j = 0; j < 4; j++) {
                    float v = fmaxf(acc[i][j][rr] + bv[j], 0.f);
                    acc[i][j][rr] = v;
                    m = fmaxf(m, v);
                }
#pragma unroll
                for (int o = 1; o < 16; o <<= 1) m = fmaxf(m, __shfl_xor(m, o, 64));
                if (l16 == 0) sred[0][colhalf][wrow + i * 16 + quad * 4 + rr] = m;
            }
        __syncthreads();
#pragma unroll
        for (int i = 0; i < 4; i++)
#pragma unroll
            for (int rr = 0; rr < 4; rr++) {
                int r2 = wrow + i * 16 + quad * 4 + rr;
                Mp[i][rr] = fmaxf(sred[0][0][r2], sred[0][1][r2]);
                float s = 0.f;
#pragma unroll
                for (int j = 0; j < 4; j++) s += __expf(acc[i][j][rr] - Mp[i][rr]);
#pragma unroll
                for (int o = 1; o < 16; o <<= 1) s += __shfl_xor(s, o, 64);
                if (l16 == 0) sred[1][colhalf][r2] = s;
            }
        __syncthreads();
#pragma unroll
        for (int i = 0; i < 4; i++)
#pragma unroll
            for (int rr = 0; rr < 4; rr++) {
                int r2 = wrow + i * 16 + quad * 4 + rr;
                long crow = (long)row0 + r2;
                if (crow < M) {
                    float lg = __logf(sred[1][0][r2] + sred[1][1][r2]);
#pragma unroll
                    for (int j = 0; j < 4; j++)
                        stf(Cb, crow * 128 + wcol + j * 16 + l16,
                            acc[i][j][rr] - Mp[i][rr] - lg, isf);
                }
            }
        return;
    }

    const long colOff = (long)bz * colOffDim;
    float* Cfp = Cf ? Cf + (long)bz * cBatch : nullptr;
#pragma unroll
    for (int i = 0; i < 4; i++)
#pragma unroll
        for (int j = 0; j < 4; j++)
#pragma unroll
            for (int r2 = 0; r2 < 4; r2++) {
                long crow = row0 + wrow + i * 16 + quad * 4 + r2;
                long ccol = n0 + wcol + j * 16 + l16;
                float v = acc[i][j][r2];
                if (MODE == 1) {
                    ((u16*)Cb)[crow * ldc + colOff + ccol] = f2b(v);
                } else if (MODE == 2) {
                    Cfp[crow * ldc + ccol] = v + ldf(bias, ccol, isf);
                } else if (MODE == 3) {
                    Cfp[crow * ldc + ccol] += v;
                } else {
                    Cfp[crow * ldc + ccol] = v;
                }
            }
}

// sum split partials + root, relu, row log_softmax [1024,1024] -> flag-aware out
__global__ void softmax2_kernel(const float* __restrict__ Zr, const float* __restrict__ Zp,
                                void* __restrict__ out, long outOff, int nsplit,
                                const int* __restrict__ flags) {
    int row = blockIdx.x;
    int t = threadIdx.x;
    __shared__ float red[4];
    float4 v = ((const float4*)Zr)[(long)row * 256 + t];
    for (int s = 0; s < nsplit; s++) {
        float4 p = ((const float4*)Zp)[(long)s * 262144 + (long)row * 256 + t];
        v.x += p.x; v.y += p.y; v.z += p.z; v.w += p.w;
    }
    float z[4] = {fmaxf(v.x, 0.f), fmaxf(v.y, 0.f), fmaxf(v.z, 0.f), fmaxf(v.w, 0.f)};
    float m = fmaxf(fmaxf(z[0], z[1]), fmaxf(z[2], z[3]));
#pragma unroll
    for (int o = 1; o < 64; o <<= 1) m = fmaxf(m, __shfl_xor(m, o, 64));
    int wave = t >> 6, lane = t & 63;
    if (lane == 0) red[wave] = m;
    __syncthreads();
    m = fmaxf(fmaxf(red[0], red[1]), fmaxf(red[2], red[3]));
    __syncthreads();
    float s4 = __expf(z[0] - m) + __expf(z[1] - m) + __expf(z[2] - m) + __expf(z[3] - m);
#pragma unroll
    for (int o = 1; o < 64; o <<= 1) s4 += __shfl_xor(s4, o, 64);
    if (lane == 0) red[wave] = s4;
    __syncthreads();
    float lg = __logf(red[0] + red[1] + red[2] + red[3]);
    long base = outOff + (long)row * 1024 + t * 4;
    if (flags[0]) {
        float4 o = {z[0] - m - lg, z[1] - m - lg, z[2] - m - lg, z[3] - m - lg};
        ((float4*)out)[base >> 2] = o;
    } else {
        u64 p = (u64)f2b(z[0] - m - lg) | ((u64)f2b(z[1] - m - lg) << 16) |
                ((u64)f2b(z[2] - m - lg) << 32) | ((u64)f2b(z[3] - m - lg) << 48);
        ((u64*)out)[base >> 2] = p;
    }
}

// ---------------- launch ----------------

extern "C" void kernel_launch(void* const* d_in, const int* in_sizes, int n_in,
                              void* d_out, int out_size, void* d_ws, size_t ws_size,
                              hipStream_t stream) {
    const void* x_g1 = d_in[0];
    const void* W    = d_in[1];
    const void* bstc = d_in[2];
    const void* x_g2 = d_in[3];
    const void* basis= d_in[4];
    const void* att  = d_in[5];
    const void* root = d_in[6];
    const void* brg  = d_in[7];
    const int* ei1   = (const int*)d_in[8];
    const int* ei2   = (const int*)d_in[9];
    const int* et2   = (const int*)d_in[10];
    const int N1 = in_sizes[0] / 128;
    const int E1 = in_sizes[8] / 2;
    const int E2 = in_sizes[9] / 2;

    const size_t MB = 1ull << 20;
    const int cCH[7] = {15, 10, 6, 5, 3, 2, 1};
    const int cNS[7] = { 8,  8, 8, 8, 8, 4, 2};
    int CH = 1, NS = 1, USE_XB = 1;
    bool found = false;
    for (int pass = 0; pass < 2 && !found; pass++) {
        size_t floorP1 = pass == 0 ? 68 * MB : 42 * MB;
        for (int c = 0; c < 7; c++) {
            size_t chunk = (size_t)cCH[c] * 6 * MB;   // Abf + ST + basTc, all bf16
            size_t scratch = chunk > floorP1 ? chunk : floorP1;
            size_t need = 11 * MB + (size_t)cNS[c] * 4 * MB + scratch;
            if (need <= ws_size) {
                CH = cCH[c]; NS = cNS[c]; USE_XB = (pass == 0); found = true; break;
            }
        }
    }
    if (!found) { CH = 1; NS = 1; USE_XB = 0; }
    const int NC = 30 / CH;
    const int kSp = CH * 1024 / NS;

    char* ws = (char*)d_ws;
    u16*   XT    = (u16*)(ws + 0);                  // 2MB
    u16*   rootT = (u16*)(ws + 2 * MB);             // 2MB
    u16*   Xbf   = (u16*)(ws + 4 * MB);             // 2MB
    u16*   WT    = (u16*)(ws + 6 * MB);             // 32KB
    int*   deg2  = (int*)(ws + 6 * MB + 65536);     // 4KB
    int*   off2  = (int*)(ws + 6 * MB + 73728);     // 4.1KB
    int*   cur2  = (int*)(ws + 6 * MB + 81920);     // 4KB
    int*   bsum2 = (int*)(ws + 6 * MB + 90112);     // 512B
    int*   flags = (int*)(ws + 6 * MB + 98304);     // 8B
    u32*   elist2= (u32*)(ws + 6 * MB + 131072);    // 800KB (E2*4)
    float* Zr    = (float*)(ws + 7 * MB);           // 4MB
    float* Zp    = (float*)(ws + 11 * MB);          // NS*4MB
    char*  S     = ws + 11 * MB + (size_t)NS * 4 * MB;
    // part1 overlay in S
    int* deg1  = (int*)(S);                          // 512KB
    int* sbCnt = (int*)(S + 512 * 1024);             // 256KB (8*NB1 ints)
    int* sbCur = (int*)(S + 768 * 1024);             // 256KB
    int* off1  = (int*)(S + 1 * MB);                 // 512KB
    int* bsum  = (int*)(S + 1536 * 1024);            // small
    u32* pair1 = (u32*)(S + 2 * MB);                 // E1*4 = 6.4MB
    int* elist = (int*)(S + 9 * MB);                 // E1*4 = 6.4MB
    u16* xg1b  = (u16*)(S + 16 * MB);                // 25.6MB
    u16* aggbf = (u16*)(S + (USE_XB ? 42 * MB : 16 * MB));  // 25.6MB
    // part2 chunk overlay in S (no fp32 Af anymore -- scatter writes bf16 directly)
    u16*   Abf   = (u16*)S;                           // CH*2MB
    u16*   ST    = (u16*)(S + (size_t)CH * 2 * MB);   // CH*2MB
    u16*   basTc = (u16*)(S + (size_t)CH * 4 * MB);   // CH*2MB

    detect_kernel<<<1, 64, 0, stream>>>((const u32*)x_g1, (const u32*)ei1, flags);

    hipMemsetAsync(deg1, 0, 786432, stream);             // deg1 + sbCnt
    hipMemsetAsync(deg2, 0, 4096, stream);
    hipMemsetAsync(cur2, 0, 4096, stream);

    // ---- Part 1: STCConv + fused log_softmax ----
    const int NB1 = (N1 + 127) >> 7;
    const int segLen = (E1 + 7) / 8;
    const int bps = (segLen + 255) / 256;
    count2_kernel<<<8 * bps, 256, 0, stream>>>(ei1, E1, segLen, deg1, sbCnt, NB1, flags);
    int nb1 = (N1 + 1023) / 1024;
    scan_block_kernel<<<nb1, 1024, 0, stream>>>(deg1, off1, bsum, N1);
    scan_small_kernel<<<1, 128, 0, stream>>>(bsum, nb1);
    scan_add_kernel<<<nb1, 1024, 0, stream>>>(off1, bsum, N1, E1);
    subscan_kernel<<<(NB1 + 255) / 256, 256, 0, stream>>>(off1, sbCnt, sbCur, NB1, N1);
    presort_kernel<<<8 * bps, 256, 0, stream>>>(ei1, E1, segLen, sbCur, NB1, pair1, flags);
    bucketfill_kernel<<<NB1, 256, 0, stream>>>(pair1, off1, NB1, N1, E1, elist);
    if (USE_XB) {
        long n4 = (long)N1 * 32;
        cvt4_kernel<<<(int)((n4 + 255) / 256), 256, 0, stream>>>(x_g1, (u64*)xg1b, n4, flags);
    }
    agg_kernel<<<(N1 + 3) / 4, 256, 0, stream>>>(x_g1, (const u32*)xg1b, off1, elist,
                                                 (u32*)aggbf, N1, flags, USE_XB);
    transpose_kernel<<<dim3(4, 4), dim3(32, 8), 0, stream>>>(W, 0, WT, 128, 128, flags);
    gemm_bt<0><<<dim3((N1 + 127) / 128, 1, 1), 256, 0, stream>>>(
        aggbf, 0, WT, nullptr, d_out, bstc, flags, N1, 128, 128, 128, 0, 0, 0, 128);

    // ---- Part 2: RGCNConv (basis), chunked, dst-sorted LDS scatter ----
    count_kernel<<<(E2 + 255) / 256, 256, 0, stream>>>(ei2, E2, deg2, flags);
    scan_block_kernel<<<1, 1024, 0, stream>>>(deg2, off2, bsum2, 1024);
    scan_small_kernel<<<1, 128, 0, stream>>>(bsum2, 1);
    scan_add_kernel<<<1, 1024, 0, stream>>>(off2, bsum2, 1024, E2);
    fill2_kernel<<<(E2 + 255) / 256, 256, 0, stream>>>(ei2, et2, E2, off2, cur2,
                                                       elist2, flags);
    cvt4_kernel<<<1024, 256, 0, stream>>>(x_g2, (u64*)Xbf, 262144, flags);
    transpose_kernel<<<dim3(32, 32), dim3(32, 8), 0, stream>>>(x_g2, 0, XT, 1024, 1024, flags);
    transpose_kernel<<<dim3(32, 32), dim3(32, 8), 0, stream>>>(root, 0, rootT, 1024, 1024, flags);
    gemm_bt<2><<<dim3(8, 8, 1), 256, 0, stream>>>(
        Xbf, 0, rootT, Zr, nullptr, brg, flags, 1024, 1024, 1024, 1024, 0, 0, 0, 1024);

    for (int c = 0; c < NC; c++) {
        scatterA_lds_kernel<<<1024, 256, 0, stream>>>(elist2, off2, att, Abf,
                                                      c * CH, CH, flags);
        transpose_kernel<<<dim3(32, CH * 32), dim3(32, 8), 0, stream>>>(
            basis, (long)c * CH * 1048576, basTc, CH * 1024, 1024, flags);
        gemm_bt<1><<<dim3(8, 8, CH), 256, 0, stream>>>(
            Abf, 1048576, XT, nullptr, ST, nullptr, flags,
            1024, 1024, 1024, CH * 1024, 1024, 0, 0, 1024);
        if (c == 0) {
            gemm_bt<4><<<dim3(8, 8, NS), 256, 0, stream>>>(
                ST, 0, basTc, Zp, nullptr, nullptr, flags,
                1024, CH * 1024, CH * 1024, 1024, 0, 1048576, kSp, kSp);
        } else {
            gemm_bt<3><<<dim3(8, 8, NS), 256, 0, stream>>>(
                ST, 0, basTc, Zp, nullptr, nullptr, flags,
                1024, CH * 1024, CH * 1024, 1024, 0, 1048576, kSp, kSp);
        }
    }
    softmax2_kernel<<<1024, 256, 0, stream>>>(Zr, Zp, d_out, (long)N1 * 128, NS, flags);
}

// Round 5
// 882.655 us; speedup vs baseline: 1.1950x; 1.1950x over previous
//
#include <hip/hip_runtime.h>

typedef unsigned short u16;
typedef unsigned int u32;
typedef unsigned long long u64;
typedef __attribute__((ext_vector_type(8))) short short8;
typedef __attribute__((ext_vector_type(4))) float floatx4;

#define NBMAX 2048

__device__ __forceinline__ float b2f(u16 u) {
    u32 x = ((u32)u) << 16; float f; __builtin_memcpy(&f, &x, 4); return f;
}
__device__ __forceinline__ u16 f2b(float f) {
    u32 x; __builtin_memcpy(&x, &f, 4);
    u32 r = (x + 0x7fffu + ((x >> 16) & 1u)) >> 16;
    return (u16)r;
}
__device__ __forceinline__ float ldf(const void* p, long i, int isf) {
    return isf ? ((const float*)p)[i] : b2f(((const u16*)p)[i]);
}
__device__ __forceinline__ void stf(void* p, long i, float v, int isf) {
    if (isf) ((float*)p)[i] = v; else ((u16*)p)[i] = f2b(v);
}
__device__ __forceinline__ int ldidx(const int* w, long i, int is64) {
    return is64 ? w[2 * i] : w[i];
}
// async global->LDS, 16B per lane. LDS dst = wave-uniform base + lane*16.
__device__ __forceinline__ void gload16(const u16* g, u16* l) {
    __builtin_amdgcn_global_load_lds((const __attribute__((address_space(1))) void*)g,
                                     (__attribute__((address_space(3))) void*)l, 16, 0, 0);
}

// ---------------- dtype detection (1 wave) ----------------
__global__ void detect_kernel(const u32* __restrict__ xw, const u32* __restrict__ iw,
                              int* __restrict__ flags) {
    int lane = threadIdx.x;
    u32 w = xw[lane];
    u32 b1 = (w >> 8) & 0x7f;
    int isbf = (b1 >= 0x38 && b1 <= 0x41) ? 1 : 0;
    int cbf = __popcll(__ballot(isbf));
    u32 hi = iw[2 * lane + 1];
    int cz = __popcll(__ballot(hi == 0u));
    if (lane == 0) {
        flags[0] = (cbf < 32) ? 1 : 0;        // 1 = fp32
        flags[1] = (cz >= 56) ? 1 : 0;        // 1 = int64
    }
}

// ---------------- graph utility kernels ----------------

__global__ void count_kernel(const int* __restrict__ eiw, int E, int* __restrict__ cnt,
                             const int* __restrict__ flags) {
    int e = blockIdx.x * 256 + threadIdx.x;
    if (e < E) atomicAdd(&cnt[ldidx(eiw, (long)E + e, flags[1])], 1);
}

// LDS-privatized bucket histogram (bucket = dst>>7). One global atomic per
// nonzero bucket per block -- no per-edge global atomics.
__global__ __launch_bounds__(256)
void bcount_kernel(const int* __restrict__ eiw, int E, int chunk,
                   int* __restrict__ bcnt, int NB, const int* __restrict__ flags) {
    __shared__ int h[NBMAX];
    int t = threadIdx.x;
    for (int i = t; i < NB; i += 256) h[i] = 0;
    __syncthreads();
    int is64 = flags[1];
    int lo = blockIdx.x * chunk;
    int hi = lo + chunk; if (hi > E) hi = E;
    for (int e = lo + t; e < hi; e += 256)
        atomicAdd(&h[ldidx(eiw, (long)E + e, is64) >> 7], 1);
    __syncthreads();
    for (int i = t; i < NB; i += 256)
        if (h[i]) atomicAdd(&bcnt[i], h[i]);
}

// exclusive scan over NB<=2048 bucket counts; writes boff[0..NB] and bcur copy.
__global__ void bscan_kernel(const int* __restrict__ bcnt, int* __restrict__ boff,
                             int* __restrict__ bcur, int NB) {
    __shared__ int sm[1024];
    int t = threadIdx.x;
    int a = (2 * t < NB) ? bcnt[2 * t] : 0;
    int b = (2 * t + 1 < NB) ? bcnt[2 * t + 1] : 0;
    int s = a + b;
    sm[t] = s;
    __syncthreads();
    for (int o = 1; o < 1024; o <<= 1) {
        int x = (t >= o) ? sm[t - o] : 0;
        __syncthreads();
        sm[t] += x;
        __syncthreads();
    }
    int ex = sm[t] - s;
    if (2 * t < NB) { boff[2 * t] = ex; bcur[2 * t] = ex; }
    if (2 * t + 1 < NB) { boff[2 * t + 1] = ex + a; bcur[2 * t + 1] = ex + a; }
    if (t == 1023) boff[NB] = sm[1023];
}

// scatter packed (dlow<<25 | src) into bucket-grouped pair buffer. Each block
// reserves a contiguous range per bucket (one global atomic per nonzero bucket),
// then places edges via LDS rank cursors -- no per-edge global atomics.
__global__ __launch_bounds__(256)
void bscatter_kernel(const int* __restrict__ eiw, int E, int chunk,
                     int* __restrict__ bcur, int NB, u32* __restrict__ pair,
                     const int* __restrict__ flags) {
    __shared__ int h[NBMAX];
    __shared__ int cur[NBMAX];
    int t = threadIdx.x;
    for (int i = t; i < NB; i += 256) h[i] = 0;
    __syncthreads();
    int is64 = flags[1];
    int lo = blockIdx.x * chunk;
    int hi = lo + chunk; if (hi > E) hi = E;
    for (int e = lo + t; e < hi; e += 256)
        atomicAdd(&h[ldidx(eiw, (long)E + e, is64) >> 7], 1);
    __syncthreads();
    for (int i = t; i < NB; i += 256) {
        int c = h[i];
        h[i] = c ? atomicAdd(&bcur[i], c) : 0;   // h becomes global base
        cur[i] = 0;
    }
    __syncthreads();
    for (int e = lo + t; e < hi; e += 256) {
        int src = ldidx(eiw, e, is64);
        int d = ldidx(eiw, (long)E + e, is64);
        int b = d >> 7;
        int p = atomicAdd(&cur[b], 1);
        pair[h[b] + p] = ((u32)(d & 127) << 25) | (u32)src;
    }
}

// per-bucket: LDS per-dst count + 128-wide prefix -> writes off1 directly,
// then places elist via LDS cursors. No global scan over N1 needed.
__global__ __launch_bounds__(256)
void bucketfill2_kernel(const u32* __restrict__ pair, const int* __restrict__ boff,
                        int NB, int N1, int* __restrict__ off1, int* __restrict__ elist) {
    __shared__ int cnt[128], pre[128], soff[128], cur[128];
    int b = blockIdx.x, t = threadIdx.x;
    int lo = boff[b], hi = boff[b + 1];
    if (t < 128) cnt[t] = 0;
    __syncthreads();
    for (int i = lo + t; i < hi; i += 256)
        atomicAdd(&cnt[pair[i] >> 25], 1);
    __syncthreads();
    if (t < 128) pre[t] = cnt[t];
    __syncthreads();
    for (int o = 1; o < 128; o <<= 1) {
        int x = (t >= o && t < 128) ? pre[t - o] : 0;
        __syncthreads();
        if (t < 128) pre[t] += x;
        __syncthreads();
    }
    int d0 = b << 7;
    if (t < 128) {
        int s = lo + pre[t] - cnt[t];
        soff[t] = s;
        cur[t] = 0;
        if (d0 + t < N1) off1[d0 + t] = s;
    }
    if (b == NB - 1 && t == 0) off1[N1] = hi;
    __syncthreads();
    for (int i = lo + t; i < hi; i += 256) {
        u32 v = pair[i];
        int dl = v >> 25;
        int p = atomicAdd(&cur[dl], 1);
        elist[soff[dl] + p] = (int)(v & 0x1FFFFFFu);
    }
}

__global__ void scan_block_kernel(const int* __restrict__ in, int* __restrict__ out,
                                  int* __restrict__ bsum, int n) {
    __shared__ int sm[1024];
    int t = threadIdx.x;
    int i = blockIdx.x * 1024 + t;
    int v = (i < n) ? in[i] : 0;
    sm[t] = v;
    __syncthreads();
    for (int o = 1; o < 1024; o <<= 1) {
        int x = (t >= o) ? sm[t - o] : 0;
        __syncthreads();
        sm[t] += x;
        __syncthreads();
    }
    if (i < n) out[i] = sm[t] - v;
    if (t == 1023) bsum[blockIdx.x] = sm[1023];
}

__global__ void scan_small_kernel(int* __restrict__ bsum, int nb) {
    __shared__ int sm[128];
    int t = threadIdx.x;
    int v = (t < nb) ? bsum[t] : 0;
    sm[t] = v;
    __syncthreads();
    for (int o = 1; o < 128; o <<= 1) {
        int x = (t >= o) ? sm[t - o] : 0;
        __syncthreads();
        sm[t] += x;
        __syncthreads();
    }
    if (t < nb) bsum[t] = sm[t] - v;
}

__global__ void scan_add_kernel(int* __restrict__ off, const int* __restrict__ bsum,
                                int n, int total) {
    int i = blockIdx.x * 1024 + threadIdx.x;
    if (i < n) off[i] += bsum[blockIdx.x];
    if (i == 0) off[n] = total;
}

// fallback fill (only used when NB1 > NBMAX)
__global__ void fill_kernel(const int* __restrict__ eiw, int E, const int* __restrict__ off,
                            int* __restrict__ cur, int* __restrict__ elist,
                            const int* __restrict__ flags) {
    int e = blockIdx.x * 256 + threadIdx.x;
    if (e < E) {
        int is64 = flags[1];
        int d = ldidx(eiw, (long)E + e, is64);
        int p = atomicAdd(&cur[d], 1);
        elist[off[d] + p] = ldidx(eiw, e, is64);
    }
}

// G2 fill: pack (src | type<<10) per edge, grouped by dst. src<1024, type<2^22.
__global__ void fill2_kernel(const int* __restrict__ ei, const int* __restrict__ et, int E,
                             const int* __restrict__ off, int* __restrict__ cur,
                             u32* __restrict__ elist, const int* __restrict__ flags) {
    int e = blockIdx.x * 256 + threadIdx.x;
    if (e < E) {
        int is64 = flags[1];
        int s = ldidx(ei, e, is64);
        int d = ldidx(ei, (long)E + e, is64);
        int t = ldidx(et, e, is64);
        int p = atomicAdd(&cur[d], 1);
        elist[off[d] + p] = (u32)s | ((u32)t << 10);
    }
}

// fp32->bf16x4 (or bf16 copy) vectorized convert
__global__ void cvt4_kernel(const void* __restrict__ in, u64* __restrict__ out, long n4,
                            const int* __restrict__ flags) {
    long i = (long)blockIdx.x * 256 + threadIdx.x;
    if (i >= n4) return;
    if (flags[0]) {
        float4 v = ((const float4*)in)[i];
        out[i] = (u64)f2b(v.x) | ((u64)f2b(v.y) << 16) | ((u64)f2b(v.z) << 32) |
                 ((u64)f2b(v.w) << 48);
    } else {
        out[i] = ((const u64*)in)[i];
    }
}

// mean-aggregate neighbor rows (128 feats per row, one wave per node), x in bf16 (xb)
// unless useXB==0 (then raw input via flags path).
__global__ void agg_kernel(const void* __restrict__ xraw, const u32* __restrict__ xb,
                           const int* __restrict__ off, const int* __restrict__ elist,
                           u32* __restrict__ aggbf, int N, const int* __restrict__ flags,
                           int useXB) {
    int node = blockIdx.x * 4 + (threadIdx.x >> 6);
    if (node >= N) return;
    int lane = threadIdx.x & 63;
    int b = off[node], e = off[node + 1];
    float a0 = 0.f, a1 = 0.f, c0 = 0.f, c1 = 0.f;
    if (useXB) {
        int i = b;
        for (; i + 4 <= e; i += 4) {
            int s0 = elist[i], s1 = elist[i + 1], s2 = elist[i + 2], s3 = elist[i + 3];
            u32 v0 = xb[(long)s0 * 64 + lane];
            u32 v1 = xb[(long)s1 * 64 + lane];
            u32 v2 = xb[(long)s2 * 64 + lane];
            u32 v3 = xb[(long)s3 * 64 + lane];
            a0 += b2f((u16)(v0 & 0xffffu)) + b2f((u16)(v2 & 0xffffu));
            a1 += b2f((u16)(v0 >> 16)) + b2f((u16)(v2 >> 16));
            c0 += b2f((u16)(v1 & 0xffffu)) + b2f((u16)(v3 & 0xffffu));
            c1 += b2f((u16)(v1 >> 16)) + b2f((u16)(v3 >> 16));
        }
        for (; i < e; i++) {
            u32 v = xb[(long)elist[i] * 64 + lane];
            a0 += b2f((u16)(v & 0xffffu));
            a1 += b2f((u16)(v >> 16));
        }
        a0 += c0; a1 += c1;
    } else if (flags[0]) {
        const float* xf = (const float*)xraw;
        for (int i = b; i < e; i++) {
            long s = elist[i];
            a0 += xf[s * 128 + 2 * lane];
            a1 += xf[s * 128 + 2 * lane + 1];
        }
    } else {
        const u32* xu = (const u32*)xraw;
        for (int i = b; i < e; i++) {
            u32 v = xu[(long)elist[i] * 64 + lane];
            a0 += b2f((u16)(v & 0xffffu));
            a1 += b2f((u16)(v >> 16));
        }
    }
    int dg = e - b; if (dg < 1) dg = 1;
    float inv = 1.0f / (float)dg;
    aggbf[(long)node * 64 + lane] = (u32)f2b(a0 * inv) | ((u32)f2b(a1 * inv) << 16);
}

// flag-aware transpose: in (bf16 or fp32) [R,C] at element offset inOff -> out bf16 [C,R]
__global__ void transpose_kernel(const void* __restrict__ in, long inOff,
                                 u16* __restrict__ out, int R, int C,
                                 const int* __restrict__ flags) {
    __shared__ u16 tile[32][33];
    int isf = flags[0];
    int tx = threadIdx.x, ty = threadIdx.y;
    int x = blockIdx.x * 32 + tx;
#pragma unroll
    for (int i = 0; i < 4; i++) {
        int y = blockIdx.y * 32 + ty + i * 8;
        long idx = inOff + (long)y * C + x;
        tile[ty + i * 8][tx] = isf ? f2b(((const float*)in)[idx]) : ((const u16*)in)[idx];
    }
    __syncthreads();
    int x2 = blockIdx.y * 32 + tx;
#pragma unroll
    for (int i = 0; i < 4; i++) {
        int y2 = blockIdx.x * 32 + ty + i * 8;
        out[(long)y2 * R + x2] = tile[tx][ty + i * 8];
    }
}

// dst-sorted dense-A build: one workgroup per dst row d. Accumulate CH basis rows
// A[b][d][:] in LDS (fp32, ds_add_f32 atomics -- no global atomics), then write
// bf16 directly (fuses the old convert_kernel; no Af memset needed).
__global__ __launch_bounds__(256)
void scatterA_lds_kernel(const u32* __restrict__ elist, const int* __restrict__ off,
                         const void* __restrict__ att, u16* __restrict__ Abf,
                         int b0, int CH, const int* __restrict__ flags) {
    __shared__ float sA[15 * 1024];
    const int d = blockIdx.x, t = threadIdx.x;
    const int b = off[d], e = off[d + 1];
    int cnt = e - b; if (cnt < 1) cnt = 1;
    const float inv = 1.0f / (float)cnt;
    const int tot = CH << 10;
    for (int i = t; i < tot; i += 256) sA[i] = 0.f;
    __syncthreads();
    const int isf = flags[0];
    for (int i = b + t; i < e; i += 256) {
        u32 v = elist[i];
        int s = v & 1023;
        long tb = (long)(v >> 10) * 30 + b0;
        for (int bb = 0; bb < CH; bb++)
            atomicAdd(&sA[(bb << 10) + s], ldf(att, tb + bb, isf) * inv);
    }
    __syncthreads();
    const long obase = (long)d * 256 + t;
    for (int bb = 0; bb < CH; bb++) {
        int base = (bb << 10) + (t << 2);
        u64 p = (u64)f2b(sA[base]) | ((u64)f2b(sA[base + 1]) << 16) |
                ((u64)f2b(sA[base + 2]) << 32) | ((u64)f2b(sA[base + 3]) << 48);
        ((u64*)Abf)[(long)bb * 262144 + obase] = p;
    }
}

// ---------------- MFMA GEMM: C = A @ B, B pre-transposed (BT[n][k]), bf16 inputs ----------------
// m97-style global_load_lds staging (16B/lane) into UNPADDED LDS [128][32] with XOR swizzle:
// chunk q (8 u16) of row r lives at slot (q ^ ((r>>1)&3)) -> frag ds_read_b128 is 2-way (free),
// staging is lane-linear as the DMA requires.
// Grid is remapped XCD-aware (bijective, m204): contiguous nbid ranges land on one XCD,
// decoded z-major/x-fastest so one XCD processes whole batches (A_z + XT fit its 4MB L2).
// MODE 0: fused bias+relu+log_softmax -> flag-aware out (part1)
// MODE 1: Cb[crow*ldc + bz*colOffDim + ccol] = bf16(acc)   (S_b packed wide)
// MODE 2: Cf = acc + bias[col]                             (root GEMM fp32)
// MODE 3: Cf[bz] += acc                                    (split-K accumulate)
// MODE 4: Cf[bz] = acc                                     (split-K first-chunk store)
template <int MODE>
__global__ __launch_bounds__(256)
void gemm_bt(const u16* __restrict__ A, long aBatch,
             const u16* __restrict__ BT,
             float* __restrict__ Cf, void* __restrict__ Cb,
             const void* __restrict__ bias, const int* __restrict__ flags,
             int M, int lda, int ldb, int ldc,
             int colOffDim, long cBatch, int kSplitStride, int kLen) {
    __shared__ u16 As[4096];
    __shared__ u16 Bs[4096];
    __shared__ float sred[2][2][128];
    const int t = threadIdx.x;
    // ---- bijective XCD-aware remap (round-robin bid%8 -> contiguous range) ----
    const int gx = gridDim.x, gy = gridDim.y;
    const int nwg = gx * gy * gridDim.z;
    const int bid = blockIdx.x + gx * (blockIdx.y + gy * blockIdx.z);
    const int q = nwg >> 3, r = nwg & 7;
    const int xcd = bid & 7, idx = bid >> 3;
    const int nbid = (xcd < r ? xcd * (q + 1) : r * (q + 1) + (xcd - r) * q) + idx;
    const int bx = nbid % gx;
    const int by = (nbid / gx) % gy;
    const int bz = nbid / (gx * gy);

    const int isf = flags[0];
    A += (long)bz * aBatch;
    const int kBase = bz * kSplitStride;
    const int row0 = bx * 128;
    const int n0 = by * 128;
    const int lane = t & 63, wave = t >> 6;
    const int wrow = (wave >> 1) * 64, wcol = (wave & 1) * 64;
    const int quad = lane >> 4, l16 = lane & 15;

    // staging: issue h covers LDS rows h*64 + wave*16 + (lane>>2), slot lane&3
    long aoff[2], boff[2];
    u16 *ldsA[2], *ldsB[2];
#pragma unroll
    for (int h = 0; h < 2; h++) {
        int r2 = h * 64 + wave * 16 + (lane >> 2);
        int clog = (lane & 3) ^ ((r2 >> 1) & 3);
        int ga = row0 + r2; if (ga >= M) ga = M - 1;
        aoff[h] = (long)ga * lda + clog * 8;
        boff[h] = (long)(n0 + r2) * ldb + clog * 8;
        ldsA[h] = &As[(h * 64 + wave * 16) * 32];
        ldsB[h] = &Bs[(h * 64 + wave * 16) * 32];
    }
    // fragment read offsets (u16 index), constant across K
    int aidx[4], bidx[4];
#pragma unroll
    for (int i = 0; i < 4; i++) {
        int ra = wrow + i * 16 + l16;
        aidx[i] = ra * 32 + ((quad ^ ((ra >> 1) & 3)) * 8);
        int rb = wcol + i * 16 + l16;
        bidx[i] = rb * 32 + ((quad ^ ((rb >> 1) & 3)) * 8);
    }

    floatx4 acc[4][4];
#pragma unroll
    for (int i = 0; i < 4; i++)
#pragma unroll
        for (int j = 0; j < 4; j++)
            acc[i][j] = (floatx4){0.f, 0.f, 0.f, 0.f};

    for (int kt = kBase; kt < kBase + kLen; kt += 32) {
        __syncthreads();
#pragma unroll
        for (int h = 0; h < 2; h++) {
            gload16(A + aoff[h] + kt, ldsA[h]);
            gload16(BT + boff[h] + kt, ldsB[h]);
        }
        __syncthreads();
        short8 af[4], bfr[4];
#pragma unroll
        for (int i = 0; i < 4; i++) {
            af[i]  = *(const short8*)&As[aidx[i]];
            bfr[i] = *(const short8*)&Bs[bidx[i]];
        }
#pragma unroll
        for (int i = 0; i < 4; i++)
#pragma unroll
            for (int j = 0; j < 4; j++)
                acc[i][j] = __builtin_amdgcn_mfma_f32_16x16x32_bf16(af[i], bfr[j], acc[i][j], 0, 0, 0);
    }

    if (MODE == 0) {
        const int colhalf = wave & 1;
        float bv[4];
#pragma unroll
        for (int j = 0; j < 4; j++)
            bv[j] = ldf(bias, wcol + j * 16 + l16, isf);
        float Mp[4][4];
#pragma unroll
        for (int i = 0; i < 4; i++)
#pragma unroll
            for (int rr = 0; rr < 4; rr++) {
                float m = 0.f;   // relu => 0 is a safe identity
#pragma unroll
                for (int j = 0; j < 4; j++) {
                    float v = fmaxf(acc[i][j][rr] + bv[j], 0.f);
                    acc[i][j][rr] = v;
                    m = fmaxf(m, v);
                }
#pragma unroll
                for (int o = 1; o < 16; o <<= 1) m = fmaxf(m, __shfl_xor(m, o, 64));
                if (l16 == 0) sred[0][colhalf][wrow + i * 16 + quad * 4 + rr] = m;
            }
        __syncthreads();
#pragma unroll
        for (int i = 0; i < 4; i++)
#pragma unroll
            for (int rr = 0; rr < 4; rr++) {
                int r2 = wrow + i * 16 + quad * 4 + rr;
                Mp[i][rr] = fmaxf(sred[0][0][r2], sred[0][1][r2]);
                float s = 0.f;
#pragma unroll
                for (int j = 0; j < 4; j++) s += __expf(acc[i][j][rr] - Mp[i][rr]);
#pragma unroll
                for (int o = 1; o < 16; o <<= 1) s += __shfl_xor(s, o, 64);
                if (l16 == 0) sred[1][colhalf][r2] = s;
            }
        __syncthreads();
#pragma unroll
        for (int i = 0; i < 4; i++)
#pragma unroll
            for (int rr = 0; rr < 4; rr++) {
                int r2 = wrow + i * 16 + quad * 4 + rr;
                long crow = (long)row0 + r2;
                if (crow < M) {
                    float lg = __logf(sred[1][0][r2] + sred[1][1][r2]);
#pragma unroll
                    for (int j = 0; j < 4; j++)
                        stf(Cb, crow * 128 + wcol + j * 16 + l16,
                            acc[i][j][rr] - Mp[i][rr] - lg, isf);
                }
            }
        return;
    }

    const long colOff = (long)bz * colOffDim;
    float* Cfp = Cf ? Cf + (long)bz * cBatch : nullptr;
#pragma unroll
    for (int i = 0; i < 4; i++)
#pragma unroll
        for (int j = 0; j < 4; j++)
#pragma unroll
            for (int r2 = 0; r2 < 4; r2++) {
                long crow = row0 + wrow + i * 16 + quad * 4 + r2;
                long ccol = n0 + wcol + j * 16 + l16;
                float v = acc[i][j][r2];
                if (MODE == 1) {
                    ((u16*)Cb)[crow * ldc + colOff + ccol] = f2b(v);
                } else if (MODE == 2) {
                    Cfp[crow * ldc + ccol] = v + ldf(bias, ccol, isf);
                } else if (MODE == 3) {
                    Cfp[crow * ldc + ccol] += v;
                } else {
                    Cfp[crow * ldc + ccol] = v;
                }
            }
}

// sum split partials + root, relu, row log_softmax [1024,1024] -> flag-aware out
__global__ void softmax2_kernel(const float* __restrict__ Zr, const float* __restrict__ Zp,
                                void* __restrict__ out, long outOff, int nsplit,
                                const int* __restrict__ flags) {
    int row = blockIdx.x;
    int t = threadIdx.x;
    __shared__ float red[4];
    float4 v = ((const float4*)Zr)[(long)row * 256 + t];
    for (int s = 0; s < nsplit; s++) {
        float4 p = ((const float4*)Zp)[(long)s * 262144 + (long)row * 256 + t];
        v.x += p.x; v.y += p.y; v.z += p.z; v.w += p.w;
    }
    float z[4] = {fmaxf(v.x, 0.f), fmaxf(v.y, 0.f), fmaxf(v.z, 0.f), fmaxf(v.w, 0.f)};
    float m = fmaxf(fmaxf(z[0], z[1]), fmaxf(z[2], z[3]));
#pragma unroll
    for (int o = 1; o < 64; o <<= 1) m = fmaxf(m, __shfl_xor(m, o, 64));
    int wave = t >> 6, lane = t & 63;
    if (lane == 0) red[wave] = m;
    __syncthreads();
    m = fmaxf(fmaxf(red[0], red[1]), fmaxf(red[2], red[3]));
    __syncthreads();
    float s4 = __expf(z[0] - m) + __expf(z[1] - m) + __expf(z[2] - m) + __expf(z[3] - m);
#pragma unroll
    for (int o = 1; o < 64; o <<= 1) s4 += __shfl_xor(s4, o, 64);
    if (lane == 0) red[wave] = s4;
    __syncthreads();
    float lg = __logf(red[0] + red[1] + red[2] + red[3]);
    long base = outOff + (long)row * 1024 + t * 4;
    if (flags[0]) {
        float4 o = {z[0] - m - lg, z[1] - m - lg, z[2] - m - lg, z[3] - m - lg};
        ((float4*)out)[base >> 2] = o;
    } else {
        u64 p = (u64)f2b(z[0] - m - lg) | ((u64)f2b(z[1] - m - lg) << 16) |
                ((u64)f2b(z[2] - m - lg) << 32) | ((u64)f2b(z[3] - m - lg) << 48);
        ((u64*)out)[base >> 2] = p;
    }
}

// ---------------- launch ----------------

extern "C" void kernel_launch(void* const* d_in, const int* in_sizes, int n_in,
                              void* d_out, int out_size, void* d_ws, size_t ws_size,
                              hipStream_t stream) {
    const void* x_g1 = d_in[0];
    const void* W    = d_in[1];
    const void* bstc = d_in[2];
    const void* x_g2 = d_in[3];
    const void* basis= d_in[4];
    const void* att  = d_in[5];
    const void* root = d_in[6];
    const void* brg  = d_in[7];
    const int* ei1   = (const int*)d_in[8];
    const int* ei2   = (const int*)d_in[9];
    const int* et2   = (const int*)d_in[10];
    const int N1 = in_sizes[0] / 128;
    const int E1 = in_sizes[8] / 2;
    const int E2 = in_sizes[9] / 2;

    const size_t MB = 1ull << 20;
    const int cCH[7] = {15, 10, 6, 5, 3, 2, 1};
    const int cNS[7] = { 8,  8, 8, 8, 8, 4, 2};
    int CH = 1, NS = 1, USE_XB = 1;
    bool found = false;
    for (int pass = 0; pass < 2 && !found; pass++) {
        size_t floorP1 = pass == 0 ? 68 * MB : 42 * MB;
        for (int c = 0; c < 7; c++) {
            size_t chunk = (size_t)cCH[c] * 6 * MB;   // Abf + ST + basTc, all bf16
            size_t scratch = chunk > floorP1 ? chunk : floorP1;
            size_t need = 11 * MB + (size_t)cNS[c] * 4 * MB + scratch;
            if (need <= ws_size) {
                CH = cCH[c]; NS = cNS[c]; USE_XB = (pass == 0); found = true; break;
            }
        }
    }
    if (!found) { CH = 1; NS = 1; USE_XB = 0; }
    const int NC = 30 / CH;
    const int kSp = CH * 1024 / NS;

    char* ws = (char*)d_ws;
    u16*   XT    = (u16*)(ws + 0);                  // 2MB
    u16*   rootT = (u16*)(ws + 2 * MB);             // 2MB
    u16*   Xbf   = (u16*)(ws + 4 * MB);             // 2MB
    u16*   WT    = (u16*)(ws + 6 * MB);             // 32KB
    int*   deg2  = (int*)(ws + 6 * MB + 65536);     // 4KB
    int*   off2  = (int*)(ws + 6 * MB + 73728);     // 4.1KB
    int*   cur2  = (int*)(ws + 6 * MB + 81920);     // 4KB
    int*   bsum2 = (int*)(ws + 6 * MB + 90112);     // 512B
    int*   flags = (int*)(ws + 6 * MB + 98304);     // 8B
    u32*   elist2= (u32*)(ws + 6 * MB + 131072);    // 800KB (E2*4)
    float* Zr    = (float*)(ws + 7 * MB);           // 4MB
    float* Zp    = (float*)(ws + 11 * MB);          // NS*4MB
    char*  S     = ws + 11 * MB + (size_t)NS * 4 * MB;
    // part1 overlay in S
    int* off1   = (int*)(S);                         // 512KB (N1+1 ints)
    int* bktCnt = (int*)(S + 512 * 1024);            // 16KB
    int* bktOff = (int*)(S + 544 * 1024);            // 16KB
    int* bktCur = (int*)(S + 576 * 1024);            // 16KB
    int* bsum   = (int*)(S + 608 * 1024);            // fallback scan partials
    int* deg1f  = (int*)(S + 1 * MB);                // fallback only (512KB)
    int* cur1f  = (int*)(S + 1536 * 1024);           // fallback only (512KB)
    u32* pair1  = (u32*)(S + 2 * MB);                // E1*4 = 6.4MB (main path)
    int* elist  = (int*)(S + 9 * MB);                // E1*4 = 6.4MB
    u16* xg1b   = (u16*)(S + 16 * MB);               // 25.6MB
    u16* aggbf  = (u16*)(S + (USE_XB ? 42 * MB : 16 * MB));  // 25.6MB
    // part2 chunk overlay in S (no fp32 Af anymore -- scatter writes bf16 directly)
    u16*   Abf   = (u16*)S;                           // CH*2MB
    u16*   ST    = (u16*)(S + (size_t)CH * 2 * MB);   // CH*2MB
    u16*   basTc = (u16*)(S + (size_t)CH * 4 * MB);   // CH*2MB

    detect_kernel<<<1, 64, 0, stream>>>((const u32*)x_g1, (const u32*)ei1, flags);

    hipMemsetAsync(deg2, 0, 4096, stream);
    hipMemsetAsync(cur2, 0, 4096, stream);

    // ---- Part 1: STCConv + fused log_softmax ----
    const int NB1 = (N1 + 127) >> 7;
    if (NB1 <= NBMAX) {
        // LDS-privatized two-level counting sort: no per-dst global atomics,
        // off1 produced directly by bucketfill2 (no N1-wide scan chain).
        hipMemsetAsync(bktCnt, 0, (size_t)(NB1 + 1) * 4, stream);
        const int chunk = 8192;
        const int nbk = (E1 + chunk - 1) / chunk;
        bcount_kernel<<<nbk, 256, 0, stream>>>(ei1, E1, chunk, bktCnt, NB1, flags);
        bscan_kernel<<<1, 1024, 0, stream>>>(bktCnt, bktOff, bktCur, NB1);
        bscatter_kernel<<<nbk, 256, 0, stream>>>(ei1, E1, chunk, bktCur, NB1, pair1, flags);
        bucketfill2_kernel<<<NB1, 256, 0, stream>>>(pair1, bktOff, NB1, N1, off1, elist);
    } else {
        hipMemsetAsync(deg1f, 0, 1048576, stream);   // deg1f + cur1f
        count_kernel<<<(E1 + 255) / 256, 256, 0, stream>>>(ei1, E1, deg1f, flags);
        int nb1 = (N1 + 1023) / 1024;
        scan_block_kernel<<<nb1, 1024, 0, stream>>>(deg1f, off1, bsum, N1);
        scan_small_kernel<<<1, 128, 0, stream>>>(bsum, nb1);
        scan_add_kernel<<<nb1, 1024, 0, stream>>>(off1, bsum, N1, E1);
        fill_kernel<<<(E1 + 255) / 256, 256, 0, stream>>>(ei1, E1, off1, cur1f, elist, flags);
    }
    if (USE_XB) {
        long n4 = (long)N1 * 32;
        cvt4_kernel<<<(int)((n4 + 255) / 256), 256, 0, stream>>>(x_g1, (u64*)xg1b, n4, flags);
    }
    agg_kernel<<<(N1 + 3) / 4, 256, 0, stream>>>(x_g1, (const u32*)xg1b, off1, elist,
                                                 (u32*)aggbf, N1, flags, USE_XB);
    transpose_kernel<<<dim3(4, 4), dim3(32, 8), 0, stream>>>(W, 0, WT, 128, 128, flags);
    gemm_bt<0><<<dim3((N1 + 127) / 128, 1, 1), 256, 0, stream>>>(
        aggbf, 0, WT, nullptr, d_out, bstc, flags, N1, 128, 128, 128, 0, 0, 0, 128);

    // ---- Part 2: RGCNConv (basis), chunked, dst-sorted LDS scatter ----
    count_kernel<<<(E2 + 255) / 256, 256, 0, stream>>>(ei2, E2, deg2, flags);
    scan_block_kernel<<<1, 1024, 0, stream>>>(deg2, off2, bsum2, 1024);
    scan_small_kernel<<<1, 128, 0, stream>>>(bsum2, 1);
    scan_add_kernel<<<1, 1024, 0, stream>>>(off2, bsum2, 1024, E2);
    fill2_kernel<<<(E2 + 255) / 256, 256, 0, stream>>>(ei2, et2, E2, off2, cur2,
                                                       elist2, flags);
    cvt4_kernel<<<1024, 256, 0, stream>>>(x_g2, (u64*)Xbf, 262144, flags);
    transpose_kernel<<<dim3(32, 32), dim3(32, 8), 0, stream>>>(x_g2, 0, XT, 1024, 1024, flags);
    transpose_kernel<<<dim3(32, 32), dim3(32, 8), 0, stream>>>(root, 0, rootT, 1024, 1024, flags);
    gemm_bt<2><<<dim3(8, 8, 1), 256, 0, stream>>>(
        Xbf, 0, rootT, Zr, nullptr, brg, flags, 1024, 1024, 1024, 1024, 0, 0, 0, 1024);

    for (int c = 0; c < NC; c++) {
        scatterA_lds_kernel<<<1024, 256, 0, stream>>>(elist2, off2, att, Abf,
                                                      c * CH, CH, flags);
        transpose_kernel<<<dim3(32, CH * 32), dim3(32, 8), 0, stream>>>(
            basis, (long)c * CH * 1048576, basTc, CH * 1024, 1024, flags);
        gemm_bt<1><<<dim3(8, 8, CH), 256, 0, stream>>>(
            Abf, 1048576, XT, nullptr, ST, nullptr, flags,
            1024, 1024, 1024, CH * 1024, 1024, 0, 0, 1024);
        if (c == 0) {
            gemm_bt<4><<<dim3(8, 8, NS), 256, 0, stream>>>(
                ST, 0, basTc, Zp, nullptr, nullptr, flags,
                1024, CH * 1024, CH * 1024, 1024, 0, 1048576, kSp, kSp);
        } else {
            gemm_bt<3><<<dim3(8, 8, NS), 256, 0, stream>>>(
                ST, 0, basTc, Zp, nullptr, nullptr, flags,
                1024, CH * 1024, CH * 1024, 1024, 0, 1048576, kSp, kSp);
        }
    }
    softmax2_kernel<<<1024, 256, 0, stream>>>(Zr, Zp, d_out, (long)N1 * 128, NS, flags);
}

// Round 6
// 832.264 us; speedup vs baseline: 1.2673x; 1.0605x over previous
//
#include <hip/hip_runtime.h>

typedef unsigned short u16;
typedef unsigned int u32;
typedef unsigned long long u64;
typedef __attribute__((ext_vector_type(8))) short short8;
typedef __attribute__((ext_vector_type(4))) float floatx4;

#define NBMAX 2048

__device__ __forceinline__ float b2f(u16 u) {
    u32 x = ((u32)u) << 16; float f; __builtin_memcpy(&f, &x, 4); return f;
}
__device__ __forceinline__ u16 f2b(float f) {
    u32 x; __builtin_memcpy(&x, &f, 4);
    u32 r = (x + 0x7fffu + ((x >> 16) & 1u)) >> 16;
    return (u16)r;
}
__device__ __forceinline__ float ldf(const void* p, long i, int isf) {
    return isf ? ((const float*)p)[i] : b2f(((const u16*)p)[i]);
}
__device__ __forceinline__ void stf(void* p, long i, float v, int isf) {
    if (isf) ((float*)p)[i] = v; else ((u16*)p)[i] = f2b(v);
}
__device__ __forceinline__ int ldidx(const int* w, long i, int is64) {
    return is64 ? w[2 * i] : w[i];
}
// async global->LDS, 16B per lane. LDS dst = wave-uniform base + lane*16.
__device__ __forceinline__ void gload16(const u16* g, u16* l) {
    __builtin_amdgcn_global_load_lds((const __attribute__((address_space(1))) void*)g,
                                     (__attribute__((address_space(3))) void*)l, 16, 0, 0);
}

// ---------------- dtype detection (1 wave) ----------------
__global__ void detect_kernel(const u32* __restrict__ xw, const u32* __restrict__ iw,
                              int* __restrict__ flags) {
    int lane = threadIdx.x;
    u32 w = xw[lane];
    u32 b1 = (w >> 8) & 0x7f;
    int isbf = (b1 >= 0x38 && b1 <= 0x41) ? 1 : 0;
    int cbf = __popcll(__ballot(isbf));
    u32 hi = iw[2 * lane + 1];
    int cz = __popcll(__ballot(hi == 0u));
    if (lane == 0) {
        flags[0] = (cbf < 32) ? 1 : 0;        // 1 = fp32
        flags[1] = (cz >= 56) ? 1 : 0;        // 1 = int64
    }
}

// ---------------- graph utility kernels ----------------

// LDS-privatized bucket histogram (bucket = dst>>shift). One global atomic per
// nonzero bucket per block -- no per-edge global atomics.
__global__ __launch_bounds__(256)
void bcount_kernel(const int* __restrict__ eiw, int E, int chunk,
                   int* __restrict__ bcnt, int NB, int shift,
                   const int* __restrict__ flags) {
    __shared__ int h[NBMAX];
    int t = threadIdx.x;
    for (int i = t; i < NB; i += 256) h[i] = 0;
    __syncthreads();
    int is64 = flags[1];
    int lo = blockIdx.x * chunk;
    int hi = lo + chunk; if (hi > E) hi = E;
    for (int e = lo + t; e < hi; e += 256)
        atomicAdd(&h[ldidx(eiw, (long)E + e, is64) >> shift], 1);
    __syncthreads();
    for (int i = t; i < NB; i += 256)
        if (h[i]) atomicAdd(&bcnt[i], h[i]);
}

// exclusive scan over NB<=2048 bucket counts; writes boff[0..NB] and bcur copy.
__global__ void bscan_kernel(const int* __restrict__ bcnt, int* __restrict__ boff,
                             int* __restrict__ bcur, int NB) {
    __shared__ int sm[1024];
    int t = threadIdx.x;
    int a = (2 * t < NB) ? bcnt[2 * t] : 0;
    int b = (2 * t + 1 < NB) ? bcnt[2 * t + 1] : 0;
    int s = a + b;
    sm[t] = s;
    __syncthreads();
    for (int o = 1; o < 1024; o <<= 1) {
        int x = (t >= o) ? sm[t - o] : 0;
        __syncthreads();
        sm[t] += x;
        __syncthreads();
    }
    int ex = sm[t] - s;
    if (2 * t < NB) { boff[2 * t] = ex; bcur[2 * t] = ex; }
    if (2 * t + 1 < NB) { boff[2 * t + 1] = ex + a; bcur[2 * t + 1] = ex + a; }
    if (t == 1023) boff[NB] = sm[1023];
}

// G1: scatter packed (dlow<<25 | src) into bucket-grouped pair buffer. Each block
// reserves a contiguous range per bucket (one global atomic per nonzero bucket),
// then places edges via LDS rank cursors -- no per-edge global atomics.
__global__ __launch_bounds__(256)
void bscatter_kernel(const int* __restrict__ eiw, int E, int chunk,
                     int* __restrict__ bcur, int NB, u32* __restrict__ pair,
                     const int* __restrict__ flags) {
    __shared__ int h[NBMAX];
    __shared__ int cur[NBMAX];
    int t = threadIdx.x;
    for (int i = t; i < NB; i += 256) h[i] = 0;
    __syncthreads();
    int is64 = flags[1];
    int lo = blockIdx.x * chunk;
    int hi = lo + chunk; if (hi > E) hi = E;
    for (int e = lo + t; e < hi; e += 256)
        atomicAdd(&h[ldidx(eiw, (long)E + e, is64) >> 7], 1);
    __syncthreads();
    for (int i = t; i < NB; i += 256) {
        int c = h[i];
        h[i] = c ? atomicAdd(&bcur[i], c) : 0;   // h becomes global base
        cur[i] = 0;
    }
    __syncthreads();
    for (int e = lo + t; e < hi; e += 256) {
        int src = ldidx(eiw, e, is64);
        int d = ldidx(eiw, (long)E + e, is64);
        int b = d >> 7;
        int p = atomicAdd(&cur[b], 1);
        pair[h[b] + p] = ((u32)(d & 127) << 25) | (u32)src;
    }
}

// G2: bucket == dst (1024). Payload (src | type<<10) written dst-grouped directly
// into elist2 -- replaces count/scan-chain/fill2 with zero per-edge global atomics.
__global__ __launch_bounds__(256)
void bscatter2_kernel(const int* __restrict__ ei, const int* __restrict__ et, int E,
                      int chunk, int* __restrict__ bcur, u32* __restrict__ elist2,
                      const int* __restrict__ flags) {
    __shared__ int h[1024];
    __shared__ int cur[1024];
    int t = threadIdx.x;
    for (int i = t; i < 1024; i += 256) h[i] = 0;
    __syncthreads();
    int is64 = flags[1];
    int lo = blockIdx.x * chunk;
    int hi = lo + chunk; if (hi > E) hi = E;
    for (int e = lo + t; e < hi; e += 256)
        atomicAdd(&h[ldidx(ei, (long)E + e, is64)], 1);
    __syncthreads();
    for (int i = t; i < 1024; i += 256) {
        int c = h[i];
        h[i] = c ? atomicAdd(&bcur[i], c) : 0;
        cur[i] = 0;
    }
    __syncthreads();
    for (int e = lo + t; e < hi; e += 256) {
        int s = ldidx(ei, e, is64);
        int d = ldidx(ei, (long)E + e, is64);
        int ty = ldidx(et, e, is64);
        int p = atomicAdd(&cur[d], 1);
        elist2[h[d] + p] = (u32)s | ((u32)ty << 10);
    }
}

// per-bucket: LDS per-dst count + 128-wide prefix -> writes off1 directly,
// then places elist via LDS cursors. No global scan over N1 needed.
__global__ __launch_bounds__(256)
void bucketfill2_kernel(const u32* __restrict__ pair, const int* __restrict__ boff,
                        int NB, int N1, int* __restrict__ off1, int* __restrict__ elist) {
    __shared__ int cnt[128], pre[128], soff[128], cur[128];
    int b = blockIdx.x, t = threadIdx.x;
    int lo = boff[b], hi = boff[b + 1];
    if (t < 128) cnt[t] = 0;
    __syncthreads();
    for (int i = lo + t; i < hi; i += 256)
        atomicAdd(&cnt[pair[i] >> 25], 1);
    __syncthreads();
    if (t < 128) pre[t] = cnt[t];
    __syncthreads();
    for (int o = 1; o < 128; o <<= 1) {
        int x = (t >= o && t < 128) ? pre[t - o] : 0;
        __syncthreads();
        if (t < 128) pre[t] += x;
        __syncthreads();
    }
    int d0 = b << 7;
    if (t < 128) {
        int s = lo + pre[t] - cnt[t];
        soff[t] = s;
        cur[t] = 0;
        if (d0 + t < N1) off1[d0 + t] = s;
    }
    if (b == NB - 1 && t == 0) off1[N1] = hi;
    __syncthreads();
    for (int i = lo + t; i < hi; i += 256) {
        u32 v = pair[i];
        int dl = v >> 25;
        int p = atomicAdd(&cur[dl], 1);
        elist[soff[dl] + p] = (int)(v & 0x1FFFFFFu);
    }
}

// fallback path kernels (only used when NB1 > NBMAX)
__global__ void count_kernel(const int* __restrict__ eiw, int E, int* __restrict__ cnt,
                             const int* __restrict__ flags) {
    int e = blockIdx.x * 256 + threadIdx.x;
    if (e < E) atomicAdd(&cnt[ldidx(eiw, (long)E + e, flags[1])], 1);
}

__global__ void scan_block_kernel(const int* __restrict__ in, int* __restrict__ out,
                                  int* __restrict__ bsum, int n) {
    __shared__ int sm[1024];
    int t = threadIdx.x;
    int i = blockIdx.x * 1024 + t;
    int v = (i < n) ? in[i] : 0;
    sm[t] = v;
    __syncthreads();
    for (int o = 1; o < 1024; o <<= 1) {
        int x = (t >= o) ? sm[t - o] : 0;
        __syncthreads();
        sm[t] += x;
        __syncthreads();
    }
    if (i < n) out[i] = sm[t] - v;
    if (t == 1023) bsum[blockIdx.x] = sm[1023];
}

__global__ void scan_small_kernel(int* __restrict__ bsum, int nb) {
    __shared__ int sm[128];
    int t = threadIdx.x;
    int v = (t < nb) ? bsum[t] : 0;
    sm[t] = v;
    __syncthreads();
    for (int o = 1; o < 128; o <<= 1) {
        int x = (t >= o) ? sm[t - o] : 0;
        __syncthreads();
        sm[t] += x;
        __syncthreads();
    }
    if (t < nb) bsum[t] = sm[t] - v;
}

__global__ void scan_add_kernel(int* __restrict__ off, const int* __restrict__ bsum,
                                int n, int total) {
    int i = blockIdx.x * 1024 + threadIdx.x;
    if (i < n) off[i] += bsum[blockIdx.x];
    if (i == 0) off[n] = total;
}

__global__ void fill_kernel(const int* __restrict__ eiw, int E, const int* __restrict__ off,
                            int* __restrict__ cur, int* __restrict__ elist,
                            const int* __restrict__ flags) {
    int e = blockIdx.x * 256 + threadIdx.x;
    if (e < E) {
        int is64 = flags[1];
        int d = ldidx(eiw, (long)E + e, is64);
        int p = atomicAdd(&cur[d], 1);
        elist[off[d] + p] = ldidx(eiw, e, is64);
    }
}

// fp32->bf16x4 (or bf16 copy) vectorized convert
__global__ void cvt4_kernel(const void* __restrict__ in, u64* __restrict__ out, long n4,
                            const int* __restrict__ flags) {
    long i = (long)blockIdx.x * 256 + threadIdx.x;
    if (i >= n4) return;
    if (flags[0]) {
        float4 v = ((const float4*)in)[i];
        out[i] = (u64)f2b(v.x) | ((u64)f2b(v.y) << 16) | ((u64)f2b(v.z) << 32) |
                 ((u64)f2b(v.w) << 48);
    } else {
        out[i] = ((const u64*)in)[i];
    }
}

// mean-aggregate neighbor rows (128 feats per row, one wave per node), x in bf16 (xb)
// unless useXB==0 (then raw input via flags path).
__global__ void agg_kernel(const void* __restrict__ xraw, const u32* __restrict__ xb,
                           const int* __restrict__ off, const int* __restrict__ elist,
                           u32* __restrict__ aggbf, int N, const int* __restrict__ flags,
                           int useXB) {
    int node = blockIdx.x * 4 + (threadIdx.x >> 6);
    if (node >= N) return;
    int lane = threadIdx.x & 63;
    int b = off[node], e = off[node + 1];
    float a0 = 0.f, a1 = 0.f, c0 = 0.f, c1 = 0.f;
    if (useXB) {
        int i = b;
        for (; i + 4 <= e; i += 4) {
            int s0 = elist[i], s1 = elist[i + 1], s2 = elist[i + 2], s3 = elist[i + 3];
            u32 v0 = xb[(long)s0 * 64 + lane];
            u32 v1 = xb[(long)s1 * 64 + lane];
            u32 v2 = xb[(long)s2 * 64 + lane];
            u32 v3 = xb[(long)s3 * 64 + lane];
            a0 += b2f((u16)(v0 & 0xffffu)) + b2f((u16)(v2 & 0xffffu));
            a1 += b2f((u16)(v0 >> 16)) + b2f((u16)(v2 >> 16));
            c0 += b2f((u16)(v1 & 0xffffu)) + b2f((u16)(v3 & 0xffffu));
            c1 += b2f((u16)(v1 >> 16)) + b2f((u16)(v3 >> 16));
        }
        for (; i < e; i++) {
            u32 v = xb[(long)elist[i] * 64 + lane];
            a0 += b2f((u16)(v & 0xffffu));
            a1 += b2f((u16)(v >> 16));
        }
        a0 += c0; a1 += c1;
    } else if (flags[0]) {
        const float* xf = (const float*)xraw;
        for (int i = b; i < e; i++) {
            long s = elist[i];
            a0 += xf[s * 128 + 2 * lane];
            a1 += xf[s * 128 + 2 * lane + 1];
        }
    } else {
        const u32* xu = (const u32*)xraw;
        for (int i = b; i < e; i++) {
            u32 v = xu[(long)elist[i] * 64 + lane];
            a0 += b2f((u16)(v & 0xffffu));
            a1 += b2f((u16)(v >> 16));
        }
    }
    int dg = e - b; if (dg < 1) dg = 1;
    float inv = 1.0f / (float)dg;
    aggbf[(long)node * 64 + lane] = (u32)f2b(a0 * inv) | ((u32)f2b(a1 * inv) << 16);
}

// flag-aware transpose: in (bf16 or fp32) [R,C] at element offset inOff -> out bf16 [C,R]
__global__ void transpose_kernel(const void* __restrict__ in, long inOff,
                                 u16* __restrict__ out, int R, int C,
                                 const int* __restrict__ flags) {
    __shared__ u16 tile[32][33];
    int isf = flags[0];
    int tx = threadIdx.x, ty = threadIdx.y;
    int x = blockIdx.x * 32 + tx;
#pragma unroll
    for (int i = 0; i < 4; i++) {
        int y = blockIdx.y * 32 + ty + i * 8;
        long idx = inOff + (long)y * C + x;
        tile[ty + i * 8][tx] = isf ? f2b(((const float*)in)[idx]) : ((const u16*)in)[idx];
    }
    __syncthreads();
    int x2 = blockIdx.y * 32 + tx;
#pragma unroll
    for (int i = 0; i < 4; i++) {
        int y2 = blockIdx.x * 32 + ty + i * 8;
        out[(long)y2 * R + x2] = tile[tx][ty + i * 8];
    }
}

// dst-sorted dense-A build: one workgroup per dst row d. Accumulate CH basis rows
// A[b][d][:] in LDS (fp32, ds_add_f32 atomics -- no global atomics), then write
// bf16 directly (fuses the old convert_kernel; no Af memset needed).
__global__ __launch_bounds__(256)
void scatterA_lds_kernel(const u32* __restrict__ elist, const int* __restrict__ off,
                         const void* __restrict__ att, u16* __restrict__ Abf,
                         int b0, int CH, const int* __restrict__ flags) {
    __shared__ float sA[15 * 1024];
    const int d = blockIdx.x, t = threadIdx.x;
    const int b = off[d], e = off[d + 1];
    int cnt = e - b; if (cnt < 1) cnt = 1;
    const float inv = 1.0f / (float)cnt;
    const int tot = CH << 10;
    for (int i = t; i < tot; i += 256) sA[i] = 0.f;
    __syncthreads();
    const int isf = flags[0];
    for (int i = b + t; i < e; i += 256) {
        u32 v = elist[i];
        int s = v & 1023;
        long tb = (long)(v >> 10) * 30 + b0;
        for (int bb = 0; bb < CH; bb++)
            atomicAdd(&sA[(bb << 10) + s], ldf(att, tb + bb, isf) * inv);
    }
    __syncthreads();
    const long obase = (long)d * 256 + t;
    for (int bb = 0; bb < CH; bb++) {
        int base = (bb << 10) + (t << 2);
        u64 p = (u64)f2b(sA[base]) | ((u64)f2b(sA[base + 1]) << 16) |
                ((u64)f2b(sA[base + 2]) << 32) | ((u64)f2b(sA[base + 3]) << 48);
        ((u64*)Abf)[(long)bb * 262144 + obase] = p;
    }
}

// ---------------- part1 STC GEMM: C = relu(A @ WT^T + b) -> log_softmax, K=N=128 ----
// WT (128x128 bf16) staged ONCE into 4 per-K-step swizzled LDS buffers (8 gload16,
// single barrier). A fragments read DIRECTLY global->registers (16B/lane) -- no
// per-K-step barriers at all (the old kernel paid 8 barrier+vmcnt drains for 4 steps).
__global__ __launch_bounds__(256)
void gemm_stc(const u16* __restrict__ A, const u16* __restrict__ BT,
              void* __restrict__ Cb, const void* __restrict__ bias,
              const int* __restrict__ flags, int M) {
    __shared__ u16 Bs[4][4096];
    __shared__ float sred[2][2][128];
    const int t = threadIdx.x;
    const int isf = flags[0];
    const int row0 = blockIdx.x * 128;
    const int lane = t & 63, wave = t >> 6;
    const int wrow = (wave >> 1) * 64, wcol = (wave & 1) * 64;
    const int quad = lane >> 4, l16 = lane & 15;

    // stage all of BT into 4 K-step buffers, swizzled exactly like gemm_bt
#pragma unroll
    for (int kt = 0; kt < 4; kt++) {
#pragma unroll
        for (int h = 0; h < 2; h++) {
            int r2 = h * 64 + wave * 16 + (lane >> 2);
            int clog = (lane & 3) ^ ((r2 >> 1) & 3);
            gload16(BT + (long)r2 * 128 + kt * 32 + clog * 8,
                    &Bs[kt][(h * 64 + wave * 16) * 32]);
        }
    }
    // A fragment element offsets (direct global, no swizzle needed)
    u32 aoff[4];
#pragma unroll
    for (int i = 0; i < 4; i++) {
        int ga = row0 + wrow + i * 16 + l16; if (ga >= M) ga = M - 1;
        aoff[i] = (u32)ga * 128u + (u32)(quad * 8);
    }
    int bidx[4];
#pragma unroll
    for (int j = 0; j < 4; j++) {
        int rb = wcol + j * 16 + l16;
        bidx[j] = rb * 32 + ((quad ^ ((rb >> 1) & 3)) * 8);
    }
    floatx4 acc[4][4];
#pragma unroll
    for (int i = 0; i < 4; i++)
#pragma unroll
        for (int j = 0; j < 4; j++)
            acc[i][j] = (floatx4){0.f, 0.f, 0.f, 0.f};
    __syncthreads();

#pragma unroll
    for (int kt = 0; kt < 4; kt++) {
        short8 af[4], bfr[4];
#pragma unroll
        for (int i = 0; i < 4; i++)
            af[i] = *(const short8*)(A + aoff[i] + kt * 32);
#pragma unroll
        for (int j = 0; j < 4; j++)
            bfr[j] = *(const short8*)&Bs[kt][bidx[j]];
#pragma unroll
        for (int i = 0; i < 4; i++)
#pragma unroll
            for (int j = 0; j < 4; j++)
                acc[i][j] = __builtin_amdgcn_mfma_f32_16x16x32_bf16(af[i], bfr[j], acc[i][j], 0, 0, 0);
    }

    // fused bias + relu + log_softmax epilogue (identical to gemm_bt MODE 0)
    const int colhalf = wave & 1;
    float bv[4];
#pragma unroll
    for (int j = 0; j < 4; j++)
        bv[j] = ldf(bias, wcol + j * 16 + l16, isf);
    float Mp[4][4];
#pragma unroll
    for (int i = 0; i < 4; i++)
#pragma unroll
        for (int rr = 0; rr < 4; rr++) {
            float m = 0.f;
#pragma unroll
            for (int j = 0; j < 4; j++) {
                float v = fmaxf(acc[i][j][rr] + bv[j], 0.f);
                acc[i][j][rr] = v;
                m = fmaxf(m, v);
            }
#pragma unroll
            for (int o = 1; o < 16; o <<= 1) m = fmaxf(m, __shfl_xor(m, o, 64));
            if (l16 == 0) sred[0][colhalf][wrow + i * 16 + quad * 4 + rr] = m;
        }
    __syncthreads();
#pragma unroll
    for (int i = 0; i < 4; i++)
#pragma unroll
        for (int rr = 0; rr < 4; rr++) {
            int r2 = wrow + i * 16 + quad * 4 + rr;
            Mp[i][rr] = fmaxf(sred[0][0][r2], sred[0][1][r2]);
            float s = 0.f;
#pragma unroll
            for (int j = 0; j < 4; j++) s += __expf(acc[i][j][rr] - Mp[i][rr]);
#pragma unroll
            for (int o = 1; o < 16; o <<= 1) s += __shfl_xor(s, o, 64);
            if (l16 == 0) sred[1][colhalf][r2] = s;
        }
    __syncthreads();
#pragma unroll
    for (int i = 0; i < 4; i++)
#pragma unroll
        for (int rr = 0; rr < 4; rr++) {
            int r2 = wrow + i * 16 + quad * 4 + rr;
            long crow = (long)row0 + r2;
            if (crow < M) {
                float lg = __logf(sred[1][0][r2] + sred[1][1][r2]);
#pragma unroll
                for (int j = 0; j < 4; j++)
                    stf(Cb, crow * 128 + wcol + j * 16 + l16,
                        acc[i][j][rr] - Mp[i][rr] - lg, isf);
            }
        }
}

// ---------------- MFMA GEMM: C = A @ B, B pre-transposed (BT[n][k]), bf16 inputs ----------------
// m97-style global_load_lds staging (16B/lane) into UNPADDED LDS [128][32] with XOR swizzle.
// Grid is remapped XCD-aware (bijective, m204).
// MODE 1: Cb[crow*ldc + bz*colOffDim + ccol] = bf16(acc)   (S_b packed wide)
// MODE 2: Cf = acc + bias[col]                             (root GEMM fp32)
// MODE 3: Cf[bz] += acc                                    (split-K accumulate)
// MODE 4: Cf[bz] = acc                                     (split-K first-chunk store)
template <int MODE>
__global__ __launch_bounds__(256)
void gemm_bt(const u16* __restrict__ A, long aBatch,
             const u16* __restrict__ BT,
             float* __restrict__ Cf, void* __restrict__ Cb,
             const void* __restrict__ bias, const int* __restrict__ flags,
             int M, int lda, int ldb, int ldc,
             int colOffDim, long cBatch, int kSplitStride, int kLen) {
    __shared__ u16 As[4096];
    __shared__ u16 Bs[4096];
    const int t = threadIdx.x;
    // ---- bijective XCD-aware remap (round-robin bid%8 -> contiguous range) ----
    const int gx = gridDim.x, gy = gridDim.y;
    const int nwg = gx * gy * gridDim.z;
    const int bid = blockIdx.x + gx * (blockIdx.y + gy * blockIdx.z);
    const int q = nwg >> 3, r = nwg & 7;
    const int xcd = bid & 7, idx = bid >> 3;
    const int nbid = (xcd < r ? xcd * (q + 1) : r * (q + 1) + (xcd - r) * q) + idx;
    const int bx = nbid % gx;
    const int by = (nbid / gx) % gy;
    const int bz = nbid / (gx * gy);

    const int isf = flags[0];
    A += (long)bz * aBatch;
    const int kBase = bz * kSplitStride;
    const int row0 = bx * 128;
    const int n0 = by * 128;
    const int lane = t & 63, wave = t >> 6;
    const int wrow = (wave >> 1) * 64, wcol = (wave & 1) * 64;
    const int quad = lane >> 4, l16 = lane & 15;

    // staging: issue h covers LDS rows h*64 + wave*16 + (lane>>2), slot lane&3
    long aoff[2], boff[2];
    u16 *ldsA[2], *ldsB[2];
#pragma unroll
    for (int h = 0; h < 2; h++) {
        int r2 = h * 64 + wave * 16 + (lane >> 2);
        int clog = (lane & 3) ^ ((r2 >> 1) & 3);
        int ga = row0 + r2; if (ga >= M) ga = M - 1;
        aoff[h] = (long)ga * lda + clog * 8;
        boff[h] = (long)(n0 + r2) * ldb + clog * 8;
        ldsA[h] = &As[(h * 64 + wave * 16) * 32];
        ldsB[h] = &Bs[(h * 64 + wave * 16) * 32];
    }
    // fragment read offsets (u16 index), constant across K
    int aidx[4], bidx[4];
#pragma unroll
    for (int i = 0; i < 4; i++) {
        int ra = wrow + i * 16 + l16;
        aidx[i] = ra * 32 + ((quad ^ ((ra >> 1) & 3)) * 8);
        int rb = wcol + i * 16 + l16;
        bidx[i] = rb * 32 + ((quad ^ ((rb >> 1) & 3)) * 8);
    }

    floatx4 acc[4][4];
#pragma unroll
    for (int i = 0; i < 4; i++)
#pragma unroll
        for (int j = 0; j < 4; j++)
            acc[i][j] = (floatx4){0.f, 0.f, 0.f, 0.f};

    for (int kt = kBase; kt < kBase + kLen; kt += 32) {
        __syncthreads();
#pragma unroll
        for (int h = 0; h < 2; h++) {
            gload16(A + aoff[h] + kt, ldsA[h]);
            gload16(BT + boff[h] + kt, ldsB[h]);
        }
        __syncthreads();
        short8 af[4], bfr[4];
#pragma unroll
        for (int i = 0; i < 4; i++) {
            af[i]  = *(const short8*)&As[aidx[i]];
            bfr[i] = *(const short8*)&Bs[bidx[i]];
        }
#pragma unroll
        for (int i = 0; i < 4; i++)
#pragma unroll
            for (int j = 0; j < 4; j++)
                acc[i][j] = __builtin_amdgcn_mfma_f32_16x16x32_bf16(af[i], bfr[j], acc[i][j], 0, 0, 0);
    }

    const long colOff = (long)bz * colOffDim;
    float* Cfp = Cf ? Cf + (long)bz * cBatch : nullptr;
#pragma unroll
    for (int i = 0; i < 4; i++)
#pragma unroll
        for (int j = 0; j < 4; j++)
#pragma unroll
            for (int r2 = 0; r2 < 4; r2++) {
                long crow = row0 + wrow + i * 16 + quad * 4 + r2;
                long ccol = n0 + wcol + j * 16 + l16;
                float v = acc[i][j][r2];
                if (MODE == 1) {
                    ((u16*)Cb)[crow * ldc + colOff + ccol] = f2b(v);
                } else if (MODE == 2) {
                    Cfp[crow * ldc + ccol] = v + ldf(bias, ccol, isf);
                } else if (MODE == 3) {
                    Cfp[crow * ldc + ccol] += v;
                } else {
                    Cfp[crow * ldc + ccol] = v;
                }
            }
}

// sum split partials + root, relu, row log_softmax [1024,1024] -> flag-aware out
__global__ void softmax2_kernel(const float* __restrict__ Zr, const float* __restrict__ Zp,
                                void* __restrict__ out, long outOff, int nsplit,
                                const int* __restrict__ flags) {
    int row = blockIdx.x;
    int t = threadIdx.x;
    __shared__ float red[4];
    float4 v = ((const float4*)Zr)[(long)row * 256 + t];
    for (int s = 0; s < nsplit; s++) {
        float4 p = ((const float4*)Zp)[(long)s * 262144 + (long)row * 256 + t];
        v.x += p.x; v.y += p.y; v.z += p.z; v.w += p.w;
    }
    float z[4] = {fmaxf(v.x, 0.f), fmaxf(v.y, 0.f), fmaxf(v.z, 0.f), fmaxf(v.w, 0.f)};
    float m = fmaxf(fmaxf(z[0], z[1]), fmaxf(z[2], z[3]));
#pragma unroll
    for (int o = 1; o < 64; o <<= 1) m = fmaxf(m, __shfl_xor(m, o, 64));
    int wave = t >> 6, lane = t & 63;
    if (lane == 0) red[wave] = m;
    __syncthreads();
    m = fmaxf(fmaxf(red[0], red[1]), fmaxf(red[2], red[3]));
    __syncthreads();
    float s4 = __expf(z[0] - m) + __expf(z[1] - m) + __expf(z[2] - m) + __expf(z[3] - m);
#pragma unroll
    for (int o = 1; o < 64; o <<= 1) s4 += __shfl_xor(s4, o, 64);
    if (lane == 0) red[wave] = s4;
    __syncthreads();
    float lg = __logf(red[0] + red[1] + red[2] + red[3]);
    long base = outOff + (long)row * 1024 + t * 4;
    if (flags[0]) {
        float4 o = {z[0] - m - lg, z[1] - m - lg, z[2] - m - lg, z[3] - m - lg};
        ((float4*)out)[base >> 2] = o;
    } else {
        u64 p = (u64)f2b(z[0] - m - lg) | ((u64)f2b(z[1] - m - lg) << 16) |
                ((u64)f2b(z[2] - m - lg) << 32) | ((u64)f2b(z[3] - m - lg) << 48);
        ((u64*)out)[base >> 2] = p;
    }
}

// ---------------- launch ----------------

extern "C" void kernel_launch(void* const* d_in, const int* in_sizes, int n_in,
                              void* d_out, int out_size, void* d_ws, size_t ws_size,
                              hipStream_t stream) {
    const void* x_g1 = d_in[0];
    const void* W    = d_in[1];
    const void* bstc = d_in[2];
    const void* x_g2 = d_in[3];
    const void* basis= d_in[4];
    const void* att  = d_in[5];
    const void* root = d_in[6];
    const void* brg  = d_in[7];
    const int* ei1   = (const int*)d_in[8];
    const int* ei2   = (const int*)d_in[9];
    const int* et2   = (const int*)d_in[10];
    const int N1 = in_sizes[0] / 128;
    const int E1 = in_sizes[8] / 2;
    const int E2 = in_sizes[9] / 2;

    const size_t MB = 1ull << 20;
    const int cCH[7] = {15, 10, 6, 5, 3, 2, 1};
    const int cNS[7] = { 8,  8, 8, 8, 8, 4, 2};
    int CH = 1, NS = 1, USE_XB = 1;
    bool found = false;
    for (int pass = 0; pass < 2 && !found; pass++) {
        size_t floorP1 = pass == 0 ? 68 * MB : 42 * MB;
        for (int c = 0; c < 7; c++) {
            size_t chunk = (size_t)cCH[c] * 6 * MB;   // Abf + ST + basTc, all bf16
            size_t scratch = chunk > floorP1 ? chunk : floorP1;
            size_t need = 11 * MB + (size_t)cNS[c] * 4 * MB + scratch;
            if (need <= ws_size) {
                CH = cCH[c]; NS = cNS[c]; USE_XB = (pass == 0); found = true; break;
            }
        }
    }
    if (!found) { CH = 1; NS = 1; USE_XB = 0; }
    const int NC = 30 / CH;
    const int kSp = CH * 1024 / NS;

    char* ws = (char*)d_ws;
    u16*   XT    = (u16*)(ws + 0);                  // 2MB
    u16*   rootT = (u16*)(ws + 2 * MB);             // 2MB
    u16*   Xbf   = (u16*)(ws + 4 * MB);             // 2MB
    u16*   WT    = (u16*)(ws + 6 * MB);             // 32KB
    int*   deg2  = (int*)(ws + 6 * MB + 65536);     // 4KB
    int*   off2  = (int*)(ws + 6 * MB + 73728);     // 4.1KB
    int*   cur2  = (int*)(ws + 6 * MB + 81920);     // 4KB
    int*   flags = (int*)(ws + 6 * MB + 98304);     // 8B
    u32*   elist2= (u32*)(ws + 6 * MB + 131072);    // 800KB (E2*4)
    float* Zr    = (float*)(ws + 7 * MB);           // 4MB
    float* Zp    = (float*)(ws + 11 * MB);          // NS*4MB
    char*  S     = ws + 11 * MB + (size_t)NS * 4 * MB;
    // part1 overlay in S
    int* off1   = (int*)(S);                         // 512KB (N1+1 ints)
    int* bktCnt = (int*)(S + 512 * 1024);            // 16KB
    int* bktOff = (int*)(S + 544 * 1024);            // 16KB
    int* bktCur = (int*)(S + 576 * 1024);            // 16KB
    int* bsum   = (int*)(S + 608 * 1024);            // fallback scan partials
    int* deg1f  = (int*)(S + 1 * MB);                // fallback only (512KB)
    int* cur1f  = (int*)(S + 1536 * 1024);           // fallback only (512KB)
    u32* pair1  = (u32*)(S + 2 * MB);                // E1*4 = 6.4MB (main path)
    int* elist  = (int*)(S + 9 * MB);                // E1*4 = 6.4MB
    u16* xg1b   = (u16*)(S + 16 * MB);               // 25.6MB
    u16* aggbf  = (u16*)(S + (USE_XB ? 42 * MB : 16 * MB));  // 25.6MB
    // part2 chunk overlay in S
    u16*   Abf   = (u16*)S;                           // CH*2MB
    u16*   ST    = (u16*)(S + (size_t)CH * 2 * MB);   // CH*2MB
    u16*   basTc = (u16*)(S + (size_t)CH * 4 * MB);   // CH*2MB

    detect_kernel<<<1, 64, 0, stream>>>((const u32*)x_g1, (const u32*)ei1, flags);

    hipMemsetAsync(deg2, 0, 4096, stream);

    // ---- Part 1: STCConv + fused log_softmax ----
    const int NB1 = (N1 + 127) >> 7;
    if (NB1 <= NBMAX) {
        hipMemsetAsync(bktCnt, 0, (size_t)(NB1 + 1) * 4, stream);
        const int chunk = 8192;
        const int nbk = (E1 + chunk - 1) / chunk;
        bcount_kernel<<<nbk, 256, 0, stream>>>(ei1, E1, chunk, bktCnt, NB1, 7, flags);
        bscan_kernel<<<1, 1024, 0, stream>>>(bktCnt, bktOff, bktCur, NB1);
        bscatter_kernel<<<nbk, 256, 0, stream>>>(ei1, E1, chunk, bktCur, NB1, pair1, flags);
        bucketfill2_kernel<<<NB1, 256, 0, stream>>>(pair1, bktOff, NB1, N1, off1, elist);
    } else {
        hipMemsetAsync(deg1f, 0, 1048576, stream);   // deg1f + cur1f
        count_kernel<<<(E1 + 255) / 256, 256, 0, stream>>>(ei1, E1, deg1f, flags);
        int nb1 = (N1 + 1023) / 1024;
        scan_block_kernel<<<nb1, 1024, 0, stream>>>(deg1f, off1, bsum, N1);
        scan_small_kernel<<<1, 128, 0, stream>>>(bsum, nb1);
        scan_add_kernel<<<nb1, 1024, 0, stream>>>(off1, bsum, N1, E1);
        fill_kernel<<<(E1 + 255) / 256, 256, 0, stream>>>(ei1, E1, off1, cur1f, elist, flags);
    }
    if (USE_XB) {
        long n4 = (long)N1 * 32;
        cvt4_kernel<<<(int)((n4 + 255) / 256), 256, 0, stream>>>(x_g1, (u64*)xg1b, n4, flags);
    }
    agg_kernel<<<(N1 + 3) / 4, 256, 0, stream>>>(x_g1, (const u32*)xg1b, off1, elist,
                                                 (u32*)aggbf, N1, flags, USE_XB);
    transpose_kernel<<<dim3(4, 4), dim3(32, 8), 0, stream>>>(W, 0, WT, 128, 128, flags);
    gemm_stc<<<dim3((N1 + 127) / 128), 256, 0, stream>>>(aggbf, WT, d_out, bstc, flags, N1);

    // ---- Part 2: RGCNConv (basis), chunked, dst-sorted LDS scatter ----
    // G2 CSR via the same LDS-privatized machinery (bucket == dst, payload packed)
    const int chunk2 = 8192;
    const int nbk2 = (E2 + chunk2 - 1) / chunk2;
    bcount_kernel<<<nbk2, 256, 0, stream>>>(ei2, E2, chunk2, deg2, 1024, 0, flags);
    bscan_kernel<<<1, 1024, 0, stream>>>(deg2, off2, cur2, 1024);
    bscatter2_kernel<<<nbk2, 256, 0, stream>>>(ei2, et2, E2, chunk2, cur2, elist2, flags);
    cvt4_kernel<<<1024, 256, 0, stream>>>(x_g2, (u64*)Xbf, 262144, flags);
    transpose_kernel<<<dim3(32, 32), dim3(32, 8), 0, stream>>>(x_g2, 0, XT, 1024, 1024, flags);
    transpose_kernel<<<dim3(32, 32), dim3(32, 8), 0, stream>>>(root, 0, rootT, 1024, 1024, flags);
    gemm_bt<2><<<dim3(8, 8, 1), 256, 0, stream>>>(
        Xbf, 0, rootT, Zr, nullptr, brg, flags, 1024, 1024, 1024, 1024, 0, 0, 0, 1024);

    for (int c = 0; c < NC; c++) {
        scatterA_lds_kernel<<<1024, 256, 0, stream>>>(elist2, off2, att, Abf,
                                                      c * CH, CH, flags);
        transpose_kernel<<<dim3(32, CH * 32), dim3(32, 8), 0, stream>>>(
            basis, (long)c * CH * 1048576, basTc, CH * 1024, 1024, flags);
        gemm_bt<1><<<dim3(8, 8, CH), 256, 0, stream>>>(
            Abf, 1048576, XT, nullptr, ST, nullptr, flags,
            1024, 1024, 1024, CH * 1024, 1024, 0, 0, 1024);
        if (c == 0) {
            gemm_bt<4><<<dim3(8, 8, NS), 256, 0, stream>>>(
                ST, 0, basTc, Zp, nullptr, nullptr, flags,
                1024, CH * 1024, CH * 1024, 1024, 0, 1048576, kSp, kSp);
        } else {
            gemm_bt<3><<<dim3(8, 8, NS), 256, 0, stream>>>(
                ST, 0, basTc, Zp, nullptr, nullptr, flags,
                1024, CH * 1024, CH * 1024, 1024, 0, 1048576, kSp, kSp);
        }
    }
    softmax2_kernel<<<1024, 256, 0, stream>>>(Zr, Zp, d_out, (long)N1 * 128, NS, flags);
}

// Round 7
// 772.093 us; speedup vs baseline: 1.3661x; 1.0779x over previous
//
#include <hip/hip_runtime.h>

typedef unsigned short u16;
typedef unsigned int u32;
typedef unsigned long long u64;
typedef __attribute__((ext_vector_type(8))) short short8;
typedef __attribute__((ext_vector_type(4))) float floatx4;

#define NBMAX 2048

__device__ __forceinline__ float b2f(u16 u) {
    u32 x = ((u32)u) << 16; float f; __builtin_memcpy(&f, &x, 4); return f;
}
__device__ __forceinline__ u16 f2b(float f) {
    u32 x; __builtin_memcpy(&x, &f, 4);
    u32 r = (x + 0x7fffu + ((x >> 16) & 1u)) >> 16;
    return (u16)r;
}
__device__ __forceinline__ float ldf(const void* p, long i, int isf) {
    return isf ? ((const float*)p)[i] : b2f(((const u16*)p)[i]);
}
__device__ __forceinline__ void stf(void* p, long i, float v, int isf) {
    if (isf) ((float*)p)[i] = v; else ((u16*)p)[i] = f2b(v);
}
__device__ __forceinline__ int ldidx(const int* w, long i, int is64) {
    return is64 ? w[2 * i] : w[i];
}
// async global->LDS, 16B per lane. LDS dst = wave-uniform base + lane*16.
__device__ __forceinline__ void gload16(const u16* g, u16* l) {
    __builtin_amdgcn_global_load_lds((const __attribute__((address_space(1))) void*)g,
                                     (__attribute__((address_space(3))) void*)l, 16, 0, 0);
}

// ---------------- dtype detection (1 wave) ----------------
__global__ void detect_kernel(const u32* __restrict__ xw, const u32* __restrict__ iw,
                              int* __restrict__ flags) {
    int lane = threadIdx.x;
    u32 w = xw[lane];
    u32 b1 = (w >> 8) & 0x7f;
    int isbf = (b1 >= 0x38 && b1 <= 0x41) ? 1 : 0;
    int cbf = __popcll(__ballot(isbf));
    u32 hi = iw[2 * lane + 1];
    int cz = __popcll(__ballot(hi == 0u));
    if (lane == 0) {
        flags[0] = (cbf < 32) ? 1 : 0;        // 1 = fp32
        flags[1] = (cz >= 56) ? 1 : 0;        // 1 = int64
    }
}

// ---------------- graph utility kernels ----------------

// LDS-privatized bucket histogram (bucket = dst>>shift). One global atomic per
// nonzero bucket per block -- no per-edge global atomics.
__global__ __launch_bounds__(256)
void bcount_kernel(const int* __restrict__ eiw, int E, int chunk,
                   int* __restrict__ bcnt, int NB, int shift,
                   const int* __restrict__ flags) {
    __shared__ int h[NBMAX];
    int t = threadIdx.x;
    for (int i = t; i < NB; i += 256) h[i] = 0;
    __syncthreads();
    int is64 = flags[1];
    int lo = blockIdx.x * chunk;
    int hi = lo + chunk; if (hi > E) hi = E;
    for (int e = lo + t; e < hi; e += 256)
        atomicAdd(&h[ldidx(eiw, (long)E + e, is64) >> shift], 1);
    __syncthreads();
    for (int i = t; i < NB; i += 256)
        if (h[i]) atomicAdd(&bcnt[i], h[i]);
}

// exclusive scan over NB<=2048 bucket counts; writes boff[0..NB] and bcur copy.
__global__ void bscan_kernel(const int* __restrict__ bcnt, int* __restrict__ boff,
                             int* __restrict__ bcur, int NB) {
    __shared__ int sm[1024];
    int t = threadIdx.x;
    int a = (2 * t < NB) ? bcnt[2 * t] : 0;
    int b = (2 * t + 1 < NB) ? bcnt[2 * t + 1] : 0;
    int s = a + b;
    sm[t] = s;
    __syncthreads();
    for (int o = 1; o < 1024; o <<= 1) {
        int x = (t >= o) ? sm[t - o] : 0;
        __syncthreads();
        sm[t] += x;
        __syncthreads();
    }
    int ex = sm[t] - s;
    if (2 * t < NB) { boff[2 * t] = ex; bcur[2 * t] = ex; }
    if (2 * t + 1 < NB) { boff[2 * t + 1] = ex + a; bcur[2 * t + 1] = ex + a; }
    if (t == 1023) boff[NB] = sm[1023];
}

// G1: scatter packed (dlow<<25 | src) into bucket-grouped pair buffer. Each block
// reserves a contiguous range per bucket (one global atomic per nonzero bucket),
// then places edges via LDS rank cursors -- no per-edge global atomics.
__global__ __launch_bounds__(256)
void bscatter_kernel(const int* __restrict__ eiw, int E, int chunk,
                     int* __restrict__ bcur, int NB, u32* __restrict__ pair,
                     const int* __restrict__ flags) {
    __shared__ int h[NBMAX];
    __shared__ int cur[NBMAX];
    int t = threadIdx.x;
    for (int i = t; i < NB; i += 256) h[i] = 0;
    __syncthreads();
    int is64 = flags[1];
    int lo = blockIdx.x * chunk;
    int hi = lo + chunk; if (hi > E) hi = E;
    for (int e = lo + t; e < hi; e += 256)
        atomicAdd(&h[ldidx(eiw, (long)E + e, is64) >> 7], 1);
    __syncthreads();
    for (int i = t; i < NB; i += 256) {
        int c = h[i];
        h[i] = c ? atomicAdd(&bcur[i], c) : 0;   // h becomes global base
        cur[i] = 0;
    }
    __syncthreads();
    for (int e = lo + t; e < hi; e += 256) {
        int src = ldidx(eiw, e, is64);
        int d = ldidx(eiw, (long)E + e, is64);
        int b = d >> 7;
        int p = atomicAdd(&cur[b], 1);
        pair[h[b] + p] = ((u32)(d & 127) << 25) | (u32)src;
    }
}

// G2: bucket == dst (1024). Payload (src | type<<10) written dst-grouped directly
// into elist2 -- zero per-edge global atomics.
__global__ __launch_bounds__(256)
void bscatter2_kernel(const int* __restrict__ ei, const int* __restrict__ et, int E,
                      int chunk, int* __restrict__ bcur, u32* __restrict__ elist2,
                      const int* __restrict__ flags) {
    __shared__ int h[1024];
    __shared__ int cur[1024];
    int t = threadIdx.x;
    for (int i = t; i < 1024; i += 256) h[i] = 0;
    __syncthreads();
    int is64 = flags[1];
    int lo = blockIdx.x * chunk;
    int hi = lo + chunk; if (hi > E) hi = E;
    for (int e = lo + t; e < hi; e += 256)
        atomicAdd(&h[ldidx(ei, (long)E + e, is64)], 1);
    __syncthreads();
    for (int i = t; i < 1024; i += 256) {
        int c = h[i];
        h[i] = c ? atomicAdd(&bcur[i], c) : 0;
        cur[i] = 0;
    }
    __syncthreads();
    for (int e = lo + t; e < hi; e += 256) {
        int s = ldidx(ei, e, is64);
        int d = ldidx(ei, (long)E + e, is64);
        int ty = ldidx(et, e, is64);
        int p = atomicAdd(&cur[d], 1);
        elist2[h[d] + p] = (u32)s | ((u32)ty << 10);
    }
}

// per-bucket: LDS per-dst count + 128-wide prefix -> writes off1 directly,
// then places elist via LDS cursors.
__global__ __launch_bounds__(256)
void bucketfill2_kernel(const u32* __restrict__ pair, const int* __restrict__ boff,
                        int NB, int N1, int* __restrict__ off1, int* __restrict__ elist) {
    __shared__ int cnt[128], pre[128], soff[128], cur[128];
    int b = blockIdx.x, t = threadIdx.x;
    int lo = boff[b], hi = boff[b + 1];
    if (t < 128) cnt[t] = 0;
    __syncthreads();
    for (int i = lo + t; i < hi; i += 256)
        atomicAdd(&cnt[pair[i] >> 25], 1);
    __syncthreads();
    if (t < 128) pre[t] = cnt[t];
    __syncthreads();
    for (int o = 1; o < 128; o <<= 1) {
        int x = (t >= o && t < 128) ? pre[t - o] : 0;
        __syncthreads();
        if (t < 128) pre[t] += x;
        __syncthreads();
    }
    int d0 = b << 7;
    if (t < 128) {
        int s = lo + pre[t] - cnt[t];
        soff[t] = s;
        cur[t] = 0;
        if (d0 + t < N1) off1[d0 + t] = s;
    }
    if (b == NB - 1 && t == 0) off1[N1] = hi;
    __syncthreads();
    for (int i = lo + t; i < hi; i += 256) {
        u32 v = pair[i];
        int dl = v >> 25;
        int p = atomicAdd(&cur[dl], 1);
        elist[soff[dl] + p] = (int)(v & 0x1FFFFFFu);
    }
}

// fallback path kernels (only used when NB1 > NBMAX)
__global__ void count_kernel(const int* __restrict__ eiw, int E, int* __restrict__ cnt,
                             const int* __restrict__ flags) {
    int e = blockIdx.x * 256 + threadIdx.x;
    if (e < E) atomicAdd(&cnt[ldidx(eiw, (long)E + e, flags[1])], 1);
}

__global__ void scan_block_kernel(const int* __restrict__ in, int* __restrict__ out,
                                  int* __restrict__ bsum, int n) {
    __shared__ int sm[1024];
    int t = threadIdx.x;
    int i = blockIdx.x * 1024 + t;
    int v = (i < n) ? in[i] : 0;
    sm[t] = v;
    __syncthreads();
    for (int o = 1; o < 1024; o <<= 1) {
        int x = (t >= o) ? sm[t - o] : 0;
        __syncthreads();
        sm[t] += x;
        __syncthreads();
    }
    if (i < n) out[i] = sm[t] - v;
    if (t == 1023) bsum[blockIdx.x] = sm[1023];
}

__global__ void scan_small_kernel(int* __restrict__ bsum, int nb) {
    __shared__ int sm[128];
    int t = threadIdx.x;
    int v = (t < nb) ? bsum[t] : 0;
    sm[t] = v;
    __syncthreads();
    for (int o = 1; o < 128; o <<= 1) {
        int x = (t >= o) ? sm[t - o] : 0;
        __syncthreads();
        sm[t] += x;
        __syncthreads();
    }
    if (t < nb) bsum[t] = sm[t] - v;
}

__global__ void scan_add_kernel(int* __restrict__ off, const int* __restrict__ bsum,
                                int n, int total) {
    int i = blockIdx.x * 1024 + threadIdx.x;
    if (i < n) off[i] += bsum[blockIdx.x];
    if (i == 0) off[n] = total;
}

__global__ void fill_kernel(const int* __restrict__ eiw, int E, const int* __restrict__ off,
                            int* __restrict__ cur, int* __restrict__ elist,
                            const int* __restrict__ flags) {
    int e = blockIdx.x * 256 + threadIdx.x;
    if (e < E) {
        int is64 = flags[1];
        int d = ldidx(eiw, (long)E + e, is64);
        int p = atomicAdd(&cur[d], 1);
        elist[off[d] + p] = ldidx(eiw, e, is64);
    }
}

// fp32->bf16x4 (or bf16 copy) vectorized convert
__global__ void cvt4_kernel(const void* __restrict__ in, u64* __restrict__ out, long n4,
                            const int* __restrict__ flags) {
    long i = (long)blockIdx.x * 256 + threadIdx.x;
    if (i >= n4) return;
    if (flags[0]) {
        float4 v = ((const float4*)in)[i];
        out[i] = (u64)f2b(v.x) | ((u64)f2b(v.y) << 16) | ((u64)f2b(v.z) << 32) |
                 ((u64)f2b(v.w) << 48);
    } else {
        out[i] = ((const u64*)in)[i];
    }
}

// mean-aggregate neighbor rows (128 feats per row, one wave per node), x in bf16 (xb)
// unless useXB==0 (then raw input via flags path).
__global__ void agg_kernel(const void* __restrict__ xraw, const u32* __restrict__ xb,
                           const int* __restrict__ off, const int* __restrict__ elist,
                           u32* __restrict__ aggbf, int N, const int* __restrict__ flags,
                           int useXB) {
    int node = blockIdx.x * 4 + (threadIdx.x >> 6);
    if (node >= N) return;
    int lane = threadIdx.x & 63;
    int b = off[node], e = off[node + 1];
    float a0 = 0.f, a1 = 0.f, c0 = 0.f, c1 = 0.f;
    if (useXB) {
        int i = b;
        for (; i + 4 <= e; i += 4) {
            int s0 = elist[i], s1 = elist[i + 1], s2 = elist[i + 2], s3 = elist[i + 3];
            u32 v0 = xb[(long)s0 * 64 + lane];
            u32 v1 = xb[(long)s1 * 64 + lane];
            u32 v2 = xb[(long)s2 * 64 + lane];
            u32 v3 = xb[(long)s3 * 64 + lane];
            a0 += b2f((u16)(v0 & 0xffffu)) + b2f((u16)(v2 & 0xffffu));
            a1 += b2f((u16)(v0 >> 16)) + b2f((u16)(v2 >> 16));
            c0 += b2f((u16)(v1 & 0xffffu)) + b2f((u16)(v3 & 0xffffu));
            c1 += b2f((u16)(v1 >> 16)) + b2f((u16)(v3 >> 16));
        }
        for (; i < e; i++) {
            u32 v = xb[(long)elist[i] * 64 + lane];
            a0 += b2f((u16)(v & 0xffffu));
            a1 += b2f((u16)(v >> 16));
        }
        a0 += c0; a1 += c1;
    } else if (flags[0]) {
        const float* xf = (const float*)xraw;
        for (int i = b; i < e; i++) {
            long s = elist[i];
            a0 += xf[s * 128 + 2 * lane];
            a1 += xf[s * 128 + 2 * lane + 1];
        }
    } else {
        const u32* xu = (const u32*)xraw;
        for (int i = b; i < e; i++) {
            u32 v = xu[(long)elist[i] * 64 + lane];
            a0 += b2f((u16)(v & 0xffffu));
            a1 += b2f((u16)(v >> 16));
        }
    }
    int dg = e - b; if (dg < 1) dg = 1;
    float inv = 1.0f / (float)dg;
    aggbf[(long)node * 64 + lane] = (u32)f2b(a0 * inv) | ((u32)f2b(a1 * inv) << 16);
}

// flag-aware transpose: in (bf16 or fp32) [R,C] at element offset inOff -> out bf16 [C,R]
__global__ void transpose_kernel(const void* __restrict__ in, long inOff,
                                 u16* __restrict__ out, int R, int C,
                                 const int* __restrict__ flags) {
    __shared__ u16 tile[32][33];
    int isf = flags[0];
    int tx = threadIdx.x, ty = threadIdx.y;
    int x = blockIdx.x * 32 + tx;
#pragma unroll
    for (int i = 0; i < 4; i++) {
        int y = blockIdx.y * 32 + ty + i * 8;
        long idx = inOff + (long)y * C + x;
        tile[ty + i * 8][tx] = isf ? f2b(((const float*)in)[idx]) : ((const u16*)in)[idx];
    }
    __syncthreads();
    int x2 = blockIdx.y * 32 + tx;
#pragma unroll
    for (int i = 0; i < 4; i++) {
        int y2 = blockIdx.x * 32 + ty + i * 8;
        out[(long)y2 * R + x2] = tile[tx][ty + i * 8];
    }
}

// dst-sorted dense-A build: one workgroup per dst row d. Accumulate CH basis rows
// A[b][d][:] in LDS (fp32, ds_add_f32 atomics), write bf16 directly.
__global__ __launch_bounds__(256)
void scatterA_lds_kernel(const u32* __restrict__ elist, const int* __restrict__ off,
                         const void* __restrict__ att, u16* __restrict__ Abf,
                         int b0, int CH, const int* __restrict__ flags) {
    __shared__ float sA[15 * 1024];
    const int d = blockIdx.x, t = threadIdx.x;
    const int b = off[d], e = off[d + 1];
    int cnt = e - b; if (cnt < 1) cnt = 1;
    const float inv = 1.0f / (float)cnt;
    const int tot = CH << 10;
    for (int i = t; i < tot; i += 256) sA[i] = 0.f;
    __syncthreads();
    const int isf = flags[0];
    for (int i = b + t; i < e; i += 256) {
        u32 v = elist[i];
        int s = v & 1023;
        long tb = (long)(v >> 10) * 30 + b0;
        for (int bb = 0; bb < CH; bb++)
            atomicAdd(&sA[(bb << 10) + s], ldf(att, tb + bb, isf) * inv);
    }
    __syncthreads();
    const long obase = (long)d * 256 + t;
    for (int bb = 0; bb < CH; bb++) {
        int base = (bb << 10) + (t << 2);
        u64 p = (u64)f2b(sA[base]) | ((u64)f2b(sA[base + 1]) << 16) |
                ((u64)f2b(sA[base + 2]) << 32) | ((u64)f2b(sA[base + 3]) << 48);
        ((u64*)Abf)[(long)bb * 262144 + obase] = p;
    }
}

// ---------------- part1 STC GEMM: C = relu(A @ WT^T + b) -> log_softmax, K=N=128 ----
__global__ __launch_bounds__(256)
void gemm_stc(const u16* __restrict__ A, const u16* __restrict__ BT,
              void* __restrict__ Cb, const void* __restrict__ bias,
              const int* __restrict__ flags, int M) {
    __shared__ u16 Bs[4][4096];
    __shared__ float sred[2][2][128];
    const int t = threadIdx.x;
    const int isf = flags[0];
    const int row0 = blockIdx.x * 128;
    const int lane = t & 63, wave = t >> 6;
    const int wrow = (wave >> 1) * 64, wcol = (wave & 1) * 64;
    const int quad = lane >> 4, l16 = lane & 15;

#pragma unroll
    for (int kt = 0; kt < 4; kt++) {
#pragma unroll
        for (int h = 0; h < 2; h++) {
            int r2 = h * 64 + wave * 16 + (lane >> 2);
            int clog = (lane & 3) ^ ((r2 >> 1) & 3);
            gload16(BT + (long)r2 * 128 + kt * 32 + clog * 8,
                    &Bs[kt][(h * 64 + wave * 16) * 32]);
        }
    }
    u32 aoff[4];
#pragma unroll
    for (int i = 0; i < 4; i++) {
        int ga = row0 + wrow + i * 16 + l16; if (ga >= M) ga = M - 1;
        aoff[i] = (u32)ga * 128u + (u32)(quad * 8);
    }
    int bidx[4];
#pragma unroll
    for (int j = 0; j < 4; j++) {
        int rb = wcol + j * 16 + l16;
        bidx[j] = rb * 32 + ((quad ^ ((rb >> 1) & 3)) * 8);
    }
    floatx4 acc[4][4];
#pragma unroll
    for (int i = 0; i < 4; i++)
#pragma unroll
        for (int j = 0; j < 4; j++)
            acc[i][j] = (floatx4){0.f, 0.f, 0.f, 0.f};
    __syncthreads();

#pragma unroll
    for (int kt = 0; kt < 4; kt++) {
        short8 af[4], bfr[4];
#pragma unroll
        for (int i = 0; i < 4; i++)
            af[i] = *(const short8*)(A + aoff[i] + kt * 32);
#pragma unroll
        for (int j = 0; j < 4; j++)
            bfr[j] = *(const short8*)&Bs[kt][bidx[j]];
#pragma unroll
        for (int i = 0; i < 4; i++)
#pragma unroll
            for (int j = 0; j < 4; j++)
                acc[i][j] = __builtin_amdgcn_mfma_f32_16x16x32_bf16(af[i], bfr[j], acc[i][j], 0, 0, 0);
    }

    const int colhalf = wave & 1;
    float bv[4];
#pragma unroll
    for (int j = 0; j < 4; j++)
        bv[j] = ldf(bias, wcol + j * 16 + l16, isf);
    float Mp[4][4];
#pragma unroll
    for (int i = 0; i < 4; i++)
#pragma unroll
        for (int rr = 0; rr < 4; rr++) {
            float m = 0.f;
#pragma unroll
            for (int j = 0; j < 4; j++) {
                float v = fmaxf(acc[i][j][rr] + bv[j], 0.f);
                acc[i][j][rr] = v;
                m = fmaxf(m, v);
            }
#pragma unroll
            for (int o = 1; o < 16; o <<= 1) m = fmaxf(m, __shfl_xor(m, o, 64));
            if (l16 == 0) sred[0][colhalf][wrow + i * 16 + quad * 4 + rr] = m;
        }
    __syncthreads();
#pragma unroll
    for (int i = 0; i < 4; i++)
#pragma unroll
        for (int rr = 0; rr < 4; rr++) {
            int r2 = wrow + i * 16 + quad * 4 + rr;
            Mp[i][rr] = fmaxf(sred[0][0][r2], sred[0][1][r2]);
            float s = 0.f;
#pragma unroll
            for (int j = 0; j < 4; j++) s += __expf(acc[i][j][rr] - Mp[i][rr]);
#pragma unroll
            for (int o = 1; o < 16; o <<= 1) s += __shfl_xor(s, o, 64);
            if (l16 == 0) sred[1][colhalf][r2] = s;
        }
    __syncthreads();
#pragma unroll
    for (int i = 0; i < 4; i++)
#pragma unroll
        for (int rr = 0; rr < 4; rr++) {
            int r2 = wrow + i * 16 + quad * 4 + rr;
            long crow = (long)row0 + r2;
            if (crow < M) {
                float lg = __logf(sred[1][0][r2] + sred[1][1][r2]);
#pragma unroll
                for (int j = 0; j < 4; j++)
                    stf(Cb, crow * 128 + wcol + j * 16 + l16,
                        acc[i][j][rr] - Mp[i][rr] - lg, isf);
            }
        }
}

// ---------------- MFMA GEMM: C = A @ B, B pre-transposed (BT[n][k]), bf16 inputs ----------------
// BK=64: LDS [128][64] per matrix (32KB total), 8-slot XOR swizzle
// (slot = chunk ^ ((row>>1)&7)), 2 MFMA sub-steps per stage -> HALF the
// barrier+vmcnt-drain count of the BK=32 structure. kLen must be a multiple of 64.
// Grid remapped XCD-aware (bijective, m204).
// MODE 1: Cb[crow*ldc + bz*colOffDim + ccol] = bf16(acc)   (S_b packed wide)
// MODE 3: Cf[bz] += acc                                    (split-K accumulate)
// MODE 4: Cf[bz] = acc                                     (split-K store)
template <int MODE>
__global__ __launch_bounds__(256)
void gemm_bt(const u16* __restrict__ A, long aBatch,
             const u16* __restrict__ BT,
             float* __restrict__ Cf, void* __restrict__ Cb,
             const int* __restrict__ flags,
             int M, int lda, int ldb, int ldc,
             int colOffDim, long cBatch, int kSplitStride, int kLen) {
    __shared__ u16 As[8192];
    __shared__ u16 Bs[8192];
    const int t = threadIdx.x;
    // ---- bijective XCD-aware remap ----
    const int gx = gridDim.x, gy = gridDim.y;
    const int nwg = gx * gy * gridDim.z;
    const int bid = blockIdx.x + gx * (blockIdx.y + gy * blockIdx.z);
    const int q = nwg >> 3, r = nwg & 7;
    const int xcd = bid & 7, idx = bid >> 3;
    const int nbid = (xcd < r ? xcd * (q + 1) : r * (q + 1) + (xcd - r) * q) + idx;
    const int bx = nbid % gx;
    const int by = (nbid / gx) % gy;
    const int bz = nbid / (gx * gy);

    A += (long)bz * aBatch;
    const int kBase = bz * kSplitStride;
    const int row0 = bx * 128;
    const int n0 = by * 128;
    const int lane = t & 63, wave = t >> 6;
    const int wrow = (wave >> 1) * 64, wcol = (wave & 1) * 64;
    const int quad = lane >> 4, l16 = lane & 15;

    // staging: issue h covers rows h*32 + wave*8 + (lane>>3); slot lane&7 (8 u16)
    long aoff[4], boff[4];
    u16 *ldsA[4], *ldsB[4];
#pragma unroll
    for (int h = 0; h < 4; h++) {
        int r2 = h * 32 + wave * 8 + (lane >> 3);
        int clog = (lane & 7) ^ ((r2 >> 1) & 7);
        int ga = row0 + r2; if (ga >= M) ga = M - 1;
        aoff[h] = (long)ga * lda + clog * 8;
        boff[h] = (long)(n0 + r2) * ldb + clog * 8;
        ldsA[h] = &As[(h * 32 + wave * 8) * 64];
        ldsB[h] = &Bs[(h * 32 + wave * 8) * 64];
    }
    // fragment read offsets (u16 index) per sub-step kk
    int aidx[2][4], bidx[2][4];
#pragma unroll
    for (int i = 0; i < 4; i++) {
        int ra = wrow + i * 16 + l16;
        int rb = wcol + i * 16 + l16;
#pragma unroll
        for (int kk = 0; kk < 2; kk++) {
            aidx[kk][i] = ra * 64 + (((kk * 4 + quad) ^ ((ra >> 1) & 7)) * 8);
            bidx[kk][i] = rb * 64 + (((kk * 4 + quad) ^ ((rb >> 1) & 7)) * 8);
        }
    }

    floatx4 acc[4][4];
#pragma unroll
    for (int i = 0; i < 4; i++)
#pragma unroll
        for (int j = 0; j < 4; j++)
            acc[i][j] = (floatx4){0.f, 0.f, 0.f, 0.f};

    for (int kt = kBase; kt < kBase + kLen; kt += 64) {
        __syncthreads();
#pragma unroll
        for (int h = 0; h < 4; h++) {
            gload16(A + aoff[h] + kt, ldsA[h]);
            gload16(BT + boff[h] + kt, ldsB[h]);
        }
        __syncthreads();
#pragma unroll
        for (int kk = 0; kk < 2; kk++) {
            short8 af[4], bfr[4];
#pragma unroll
            for (int i = 0; i < 4; i++) {
                af[i]  = *(const short8*)&As[aidx[kk][i]];
                bfr[i] = *(const short8*)&Bs[bidx[kk][i]];
            }
#pragma unroll
            for (int i = 0; i < 4; i++)
#pragma unroll
                for (int j = 0; j < 4; j++)
                    acc[i][j] = __builtin_amdgcn_mfma_f32_16x16x32_bf16(af[i], bfr[j], acc[i][j], 0, 0, 0);
        }
    }

    const long colOff = (long)bz * colOffDim;
    float* Cfp = Cf ? Cf + (long)bz * cBatch : nullptr;
#pragma unroll
    for (int i = 0; i < 4; i++)
#pragma unroll
        for (int j = 0; j < 4; j++)
#pragma unroll
            for (int r2 = 0; r2 < 4; r2++) {
                long crow = row0 + wrow + i * 16 + quad * 4 + r2;
                long ccol = n0 + wcol + j * 16 + l16;
                float v = acc[i][j][r2];
                if (MODE == 1) {
                    ((u16*)Cb)[crow * ldc + colOff + ccol] = f2b(v);
                } else if (MODE == 3) {
                    Cfp[crow * ldc + ccol] += v;
                } else {
                    Cfp[crow * ldc + ccol] = v;
                }
            }
}

// sum root split partials + basis split partials + bias, relu, row log_softmax
__global__ void softmax2_kernel(const float* __restrict__ Zr4, const float* __restrict__ Zp,
                                const void* __restrict__ brg, void* __restrict__ out,
                                long outOff, int nsplit, const int* __restrict__ flags) {
    int row = blockIdx.x;
    int t = threadIdx.x;
    __shared__ float red[4];
    int isf = flags[0];
    float4 v;
    v.x = ldf(brg, t * 4 + 0, isf);
    v.y = ldf(brg, t * 4 + 1, isf);
    v.z = ldf(brg, t * 4 + 2, isf);
    v.w = ldf(brg, t * 4 + 3, isf);
    for (int s = 0; s < 4; s++) {
        float4 p = ((const float4*)Zr4)[(long)s * 262144 + (long)row * 256 + t];
        v.x += p.x; v.y += p.y; v.z += p.z; v.w += p.w;
    }
    for (int s = 0; s < nsplit; s++) {
        float4 p = ((const float4*)Zp)[(long)s * 262144 + (long)row * 256 + t];
        v.x += p.x; v.y += p.y; v.z += p.z; v.w += p.w;
    }
    float z[4] = {fmaxf(v.x, 0.f), fmaxf(v.y, 0.f), fmaxf(v.z, 0.f), fmaxf(v.w, 0.f)};
    float m = fmaxf(fmaxf(z[0], z[1]), fmaxf(z[2], z[3]));
#pragma unroll
    for (int o = 1; o < 64; o <<= 1) m = fmaxf(m, __shfl_xor(m, o, 64));
    int wave = t >> 6, lane = t & 63;
    if (lane == 0) red[wave] = m;
    __syncthreads();
    m = fmaxf(fmaxf(red[0], red[1]), fmaxf(red[2], red[3]));
    __syncthreads();
    float s4 = __expf(z[0] - m) + __expf(z[1] - m) + __expf(z[2] - m) + __expf(z[3] - m);
#pragma unroll
    for (int o = 1; o < 64; o <<= 1) s4 += __shfl_xor(s4, o, 64);
    if (lane == 0) red[wave] = s4;
    __syncthreads();
    float lg = __logf(red[0] + red[1] + red[2] + red[3]);
    long base = outOff + (long)row * 1024 + t * 4;
    if (isf) {
        float4 o = {z[0] - m - lg, z[1] - m - lg, z[2] - m - lg, z[3] - m - lg};
        ((float4*)out)[base >> 2] = o;
    } else {
        u64 p = (u64)f2b(z[0] - m - lg) | ((u64)f2b(z[1] - m - lg) << 16) |
                ((u64)f2b(z[2] - m - lg) << 32) | ((u64)f2b(z[3] - m - lg) << 48);
        ((u64*)out)[base >> 2] = p;
    }
}

// ---------------- launch ----------------

extern "C" void kernel_launch(void* const* d_in, const int* in_sizes, int n_in,
                              void* d_out, int out_size, void* d_ws, size_t ws_size,
                              hipStream_t stream) {
    const void* x_g1 = d_in[0];
    const void* W    = d_in[1];
    const void* bstc = d_in[2];
    const void* x_g2 = d_in[3];
    const void* basis= d_in[4];
    const void* att  = d_in[5];
    const void* root = d_in[6];
    const void* brg  = d_in[7];
    const int* ei1   = (const int*)d_in[8];
    const int* ei2   = (const int*)d_in[9];
    const int* et2   = (const int*)d_in[10];
    const int N1 = in_sizes[0] / 128;
    const int E1 = in_sizes[8] / 2;
    const int E2 = in_sizes[9] / 2;

    const size_t MB = 1ull << 20;
    const int cCH[7] = {15, 10, 6, 5, 3, 2, 1};
    const int cNS[7] = { 8,  8, 8, 8, 8, 4, 2};
    int CH = 1, NS = 1, USE_XB = 1;
    bool found = false;
    for (int pass = 0; pass < 2 && !found; pass++) {
        size_t floorP1 = pass == 0 ? 68 * MB : 42 * MB;
        for (int c = 0; c < 7; c++) {
            size_t chunk = (size_t)cCH[c] * 6 * MB;   // Abf + ST + basTc, all bf16
            size_t scratch = chunk > floorP1 ? chunk : floorP1;
            size_t need = 23 * MB + (size_t)cNS[c] * 4 * MB + scratch;
            if (need <= ws_size) {
                CH = cCH[c]; NS = cNS[c]; USE_XB = (pass == 0); found = true; break;
            }
        }
    }
    if (!found) { CH = 1; NS = 1; USE_XB = 0; }
    const int NC = 30 / CH;
    const int kSp = CH * 1024 / NS;

    char* ws = (char*)d_ws;
    u16*   XT    = (u16*)(ws + 0);                  // 2MB
    u16*   rootT = (u16*)(ws + 2 * MB);             // 2MB
    u16*   Xbf   = (u16*)(ws + 4 * MB);             // 2MB
    u16*   WT    = (u16*)(ws + 6 * MB);             // 32KB
    int*   deg2  = (int*)(ws + 6 * MB + 65536);     // 4KB
    int*   off2  = (int*)(ws + 6 * MB + 73728);     // 4.1KB
    int*   cur2  = (int*)(ws + 6 * MB + 81920);     // 4KB
    int*   flags = (int*)(ws + 6 * MB + 98304);     // 8B
    u32*   elist2= (u32*)(ws + 6 * MB + 131072);    // 800KB (E2*4)
    float* Zp    = (float*)(ws + 7 * MB);           // NS*4MB
    float* Zr4   = (float*)(ws + 7 * MB + (size_t)NS * 4 * MB);  // 16MB
    char*  S     = ws + 23 * MB + (size_t)NS * 4 * MB;
    // part1 overlay in S
    int* off1   = (int*)(S);                         // 512KB (N1+1 ints)
    int* bktCnt = (int*)(S + 512 * 1024);            // 16KB
    int* bktOff = (int*)(S + 544 * 1024);            // 16KB
    int* bktCur = (int*)(S + 576 * 1024);            // 16KB
    int* bsum   = (int*)(S + 608 * 1024);            // fallback scan partials
    int* deg1f  = (int*)(S + 1 * MB);                // fallback only (512KB)
    int* cur1f  = (int*)(S + 1536 * 1024);           // fallback only (512KB)
    u32* pair1  = (u32*)(S + 2 * MB);                // E1*4 = 6.4MB (main path)
    int* elist  = (int*)(S + 9 * MB);                // E1*4 = 6.4MB
    u16* xg1b   = (u16*)(S + 16 * MB);               // 25.6MB
    u16* aggbf  = (u16*)(S + (USE_XB ? 42 * MB : 16 * MB));  // 25.6MB
    // part2 chunk overlay in S
    u16*   Abf   = (u16*)S;                           // CH*2MB
    u16*   ST    = (u16*)(S + (size_t)CH * 2 * MB);   // CH*2MB
    u16*   basTc = (u16*)(S + (size_t)CH * 4 * MB);   // CH*2MB

    detect_kernel<<<1, 64, 0, stream>>>((const u32*)x_g1, (const u32*)ei1, flags);

    hipMemsetAsync(deg2, 0, 4096, stream);

    // ---- Part 1: STCConv + fused log_softmax ----
    const int NB1 = (N1 + 127) >> 7;
    if (NB1 <= NBMAX) {
        hipMemsetAsync(bktCnt, 0, (size_t)(NB1 + 1) * 4, stream);
        const int chunk = 8192;
        const int nbk = (E1 + chunk - 1) / chunk;
        bcount_kernel<<<nbk, 256, 0, stream>>>(ei1, E1, chunk, bktCnt, NB1, 7, flags);
        bscan_kernel<<<1, 1024, 0, stream>>>(bktCnt, bktOff, bktCur, NB1);
        bscatter_kernel<<<nbk, 256, 0, stream>>>(ei1, E1, chunk, bktCur, NB1, pair1, flags);
        bucketfill2_kernel<<<NB1, 256, 0, stream>>>(pair1, bktOff, NB1, N1, off1, elist);
    } else {
        hipMemsetAsync(deg1f, 0, 1048576, stream);   // deg1f + cur1f
        count_kernel<<<(E1 + 255) / 256, 256, 0, stream>>>(ei1, E1, deg1f, flags);
        int nb1 = (N1 + 1023) / 1024;
        scan_block_kernel<<<nb1, 1024, 0, stream>>>(deg1f, off1, bsum, N1);
        scan_small_kernel<<<1, 128, 0, stream>>>(bsum, nb1);
        scan_add_kernel<<<nb1, 1024, 0, stream>>>(off1, bsum, N1, E1);
        fill_kernel<<<(E1 + 255) / 256, 256, 0, stream>>>(ei1, E1, off1, cur1f, elist, flags);
    }
    if (USE_XB) {
        long n4 = (long)N1 * 32;
        cvt4_kernel<<<(int)((n4 + 255) / 256), 256, 0, stream>>>(x_g1, (u64*)xg1b, n4, flags);
    }
    agg_kernel<<<(N1 + 3) / 4, 256, 0, stream>>>(x_g1, (const u32*)xg1b, off1, elist,
                                                 (u32*)aggbf, N1, flags, USE_XB);
    transpose_kernel<<<dim3(4, 4), dim3(32, 8), 0, stream>>>(W, 0, WT, 128, 128, flags);
    gemm_stc<<<dim3((N1 + 127) / 128), 256, 0, stream>>>(aggbf, WT, d_out, bstc, flags, N1);

    // ---- Part 2: RGCNConv (basis), chunked, dst-sorted LDS scatter ----
    const int chunk2 = 8192;
    const int nbk2 = (E2 + chunk2 - 1) / chunk2;
    bcount_kernel<<<nbk2, 256, 0, stream>>>(ei2, E2, chunk2, deg2, 1024, 0, flags);
    bscan_kernel<<<1, 1024, 0, stream>>>(deg2, off2, cur2, 1024);
    bscatter2_kernel<<<nbk2, 256, 0, stream>>>(ei2, et2, E2, chunk2, cur2, elist2, flags);
    cvt4_kernel<<<1024, 256, 0, stream>>>(x_g2, (u64*)Xbf, 262144, flags);
    transpose_kernel<<<dim3(32, 32), dim3(32, 8), 0, stream>>>(x_g2, 0, XT, 1024, 1024, flags);
    transpose_kernel<<<dim3(32, 32), dim3(32, 8), 0, stream>>>(root, 0, rootT, 1024, 1024, flags);
    // root GEMM split-K x4 -> Zr4 partials (summed with bias in softmax2)
    gemm_bt<4><<<dim3(8, 8, 4), 256, 0, stream>>>(
        Xbf, 0, rootT, Zr4, nullptr, flags, 1024, 1024, 1024, 1024, 0, 1048576, 256, 256);

    for (int c = 0; c < NC; c++) {
        scatterA_lds_kernel<<<1024, 256, 0, stream>>>(elist2, off2, att, Abf,
                                                      c * CH, CH, flags);
        transpose_kernel<<<dim3(32, CH * 32), dim3(32, 8), 0, stream>>>(
            basis, (long)c * CH * 1048576, basTc, CH * 1024, 1024, flags);
        gemm_bt<1><<<dim3(8, 8, CH), 256, 0, stream>>>(
            Abf, 1048576, XT, nullptr, ST, flags,
            1024, 1024, 1024, CH * 1024, 1024, 0, 0, 1024);
        if (c == 0) {
            gemm_bt<4><<<dim3(8, 8, NS), 256, 0, stream>>>(
                ST, 0, basTc, Zp, nullptr, flags,
                1024, CH * 1024, CH * 1024, 1024, 0, 1048576, kSp, kSp);
        } else {
            gemm_bt<3><<<dim3(8, 8, NS), 256, 0, stream>>>(
                ST, 0, basTc, Zp, nullptr, flags,
                1024, CH * 1024, CH * 1024, 1024, 0, 1048576, kSp, kSp);
        }
    }
    softmax2_kernel<<<1024, 256, 0, stream>>>(Zr4, Zp, brg, d_out, (long)N1 * 128, NS, flags);
}